// Round 2
// baseline (837.831 us; speedup 1.0000x reference)
//
#include <hip/hip_runtime.h>

// GRU seq2seq, MI355X gfx950. Round 12: de-lockstep the wave pairs.
//   R11 counters: MfmaUtil 44% + VALUBusy 49% ~= 100% of phase time -> pipes
//   run SERIALLY. Cause: in-order issue + identical per-wave program
//   [39 MFMA][combine], both waves per SIMD in lockstep from the same barrier.
//   R12: (1) wave-group skew - waves 0-3 do [L0][L1][cL0][cL1], waves 4-7 do
//   [L1][L0][cL1][cL0]; SIMD-mates (w, w+4) thus interleave MFMA and combine.
//   (2) s_setprio(1) around MFMA clusters (now has role diversity).
//   (3) decoder FC reduce via DPP (quad_perm/row_ror adds, VALU full-rate)
//   instead of 8 serial ds_bpermute shuffles on the feedback critical path.
//   Structure otherwise identical to R11 (256 blocks x BT=8, spread-2 combine,
//   register/AGPR-resident weights, 1-barrier encoder, 2-phase decoder).

typedef unsigned short ushort_t;
typedef unsigned int uint_t;
typedef __attribute__((ext_vector_type(8))) short short8;
typedef __attribute__((ext_vector_type(4))) float f32x4;
typedef __attribute__((ext_vector_type(2))) unsigned int uintx2;

#define BT   8
#define NT   512
#define HD   128
#define TIN  336
#define TOUT 168
#define NFE  16
#define NB   256

#define SC_RZ (-1.44269504089f)   // -log2(e)
#define SC_N  (-2.88539008177f)   // -2*log2(e)

#define OFF_EWHH0 0
#define OFF_EWIH1 6144
#define OFF_EWHH1 12288
#define OFF_DWHH0 18432
#define OFF_DWIH1 24576
#define OFF_DWHH1 30720
#define OFF_EWIH0 36864
#define OFF_FW1   38400

__device__ __forceinline__ ushort_t f2bf(float f) {      // RNE (prep only)
    union { float f; uint_t u; } v; v.f = f;
    uint_t r = v.u + 0x7FFFu + ((v.u >> 16) & 1u);
    return (ushort_t)(r >> 16);
}
__device__ __forceinline__ ushort_t f2bf_h(float f) {    // round-half-up, 2 VALU
    union { float f; uint_t u; } v; v.f = f;
    return (ushort_t)((v.u + 0x8000u) >> 16);
}
__device__ __forceinline__ f32x4 splat4(float v) {
    return (f32x4){v, v, v, v};
}
__device__ __forceinline__ float sig2(float t) {         // sigmoid of pre-scaled acc
    return __builtin_amdgcn_rcpf(1.f + __builtin_amdgcn_exp2f(t));
}
__device__ __forceinline__ void barrier_lds() {
    asm volatile("s_waitcnt lgkmcnt(0)\n\ts_barrier" ::: "memory");
}

// a' = [a.lo | b.lo], b' = [a.hi | b.hi]
__device__ __forceinline__ void pl32swap(float& a, float& b) {
    uintx2 r = __builtin_amdgcn_permlane32_swap(
        __float_as_uint(a), __float_as_uint(b), false, false);
    a = __uint_as_float(r[0]);
    b = __uint_as_float(r[1]);
}
// Pack the 8 valid C-rows (rows 0-7, lanes q=0,1) across all 64 lanes.
__device__ __forceinline__ void spread2(f32x4 v, float& e0, float& e1) {
    float a0 = v[0], a2 = v[2];
    float a1 = v[1], a3 = v[3];
    pl32swap(a0, a2);
    pl32swap(a1, a3);
    e0 = a0; e1 = a1;
}

// ---- DPP 16-lane-group sum: every lane gets the sum of its 16-lane row ----
template <int CTRL>
__device__ __forceinline__ float dpp_add(float acc) {
    int x = __builtin_amdgcn_update_dpp(0, __float_as_int(acc), CTRL, 0xF, 0xF, true);
    return acc + __int_as_float(x);
}
__device__ __forceinline__ float sum16(float v) {
    v = dpp_add<0xB1>(v);    // quad_perm [1,0,3,2]  (xor 1)
    v = dpp_add<0x4E>(v);    // quad_perm [2,3,0,1]  (xor 2)
    v = dpp_add<0x124>(v);   // row_ror:4  (quad-pair)
    v = dpp_add<0x128>(v);   // row_ror:8  (opposite pair)
    return v;
}

// ---------------- prep: fp32 weights -> bf16 MFMA B-fragments ----------------
// Gate matrices PRE-SCALED: rows [0,256) by -log2e, rows [256,384) by -2log2e.
extern "C" __global__ __launch_bounds__(64)
void prep_kernel(const float* __restrict__ eWhh0, const float* __restrict__ eWih1,
                 const float* __restrict__ eWhh1, const float* __restrict__ dWhh0,
                 const float* __restrict__ dWih1, const float* __restrict__ dWhh1,
                 const float* __restrict__ eWih0, const float* __restrict__ fW1,
                 uint4* __restrict__ ws)
{
    const int g = blockIdx.x;
    const int L = threadIdx.x;
    const int n_lo = L & 15, q = L >> 4;

    const float* src; int n, kb, Ksrc, dst16; float sc;
    if (g < 576) {
        const int m = g / 96, lf = g % 96;
        const float* hs[6] = {eWhh0, eWih1, eWhh1, dWhh0, dWih1, dWhh1};
        src = hs[m];
        const int nt = lf >> 2, kf = lf & 3;
        n = nt * 16 + n_lo; kb = kf * 32 + q * 8; Ksrc = 128;
        dst16 = m * 6144 + lf * 64 + L;
        sc = (n < 2 * HD) ? SC_RZ : SC_N;
    } else if (g < 600) {
        const int nt = g - 576;
        src = eWih0; n = nt * 16 + n_lo; kb = q * 8; Ksrc = 16;
        dst16 = OFF_EWIH0 + nt * 64 + L;
        sc = (n < 2 * HD) ? SC_RZ : SC_N;
    } else {
        const int lf = g - 600;
        src = fW1; n = (lf >> 2) * 16 + n_lo; kb = (lf & 3) * 32 + q * 8; Ksrc = 128;
        dst16 = OFF_FW1 + lf * 64 + L;
        sc = 1.f;
    }

    ushort_t h[8];
    #pragma unroll
    for (int j = 0; j < 8; ++j) {
        const int k = kb + j;
        h[j] = (k < Ksrc) ? f2bf(sc * src[n * Ksrc + k]) : (ushort_t)0;
    }
    uint4 o;
    o.x = (uint_t)h[0] | ((uint_t)h[1] << 16);
    o.y = (uint_t)h[2] | ((uint_t)h[3] << 16);
    o.z = (uint_t)h[4] | ((uint_t)h[5] << 16);
    o.w = (uint_t)h[6] | ((uint_t)h[7] << 16);
    ws[dst16] = o;
}

// Spread-combine: 2 valid elements per lane (rows (q&1)*4 + hi2 + e).
__device__ __forceinline__ void combineS(const f32x4& gr, const f32x4& gz,
                                         const f32x4& gn_i, const f32x4& gn_h,
                                         float* hreg, ushort_t* wb)
{
    float r_[2], z_[2], i_[2], n_[2];
    spread2(gr,   r_[0], r_[1]);
    spread2(gz,   z_[0], z_[1]);
    spread2(gn_i, i_[0], i_[1]);
    spread2(gn_h, n_[0], n_[1]);
    #pragma unroll
    for (int e = 0; e < 2; ++e) {
        const float rg = sig2(r_[e]);
        const float zg = sig2(z_[e]);
        const float ng = fmaf(2.f, sig2(i_[e] + rg * n_[e]), -1.f);
        const float hn = fmaf(zg, hreg[e] - ng, ng);
        hreg[e] = hn;
        wb[e * 8] = f2bf_h(hn);
    }
}

extern "C" __global__ __launch_bounds__(NT, 2)
void gru_seq2seq_kernel(
    const float* __restrict__ x,
    const float* __restrict__ ebih0, const float* __restrict__ ebhh0,
    const float* __restrict__ ebih1, const float* __restrict__ ebhh1,
    const float* __restrict__ dWih0, const float* __restrict__ dbih0,
    const float* __restrict__ dbhh0,
    const float* __restrict__ dbih1, const float* __restrict__ dbhh1,
    const float* __restrict__ fb1, const float* __restrict__ fW2,
    const float* __restrict__ fb2,
    const short8* __restrict__ wf,
    float* __restrict__ out)
{
    __shared__ ushort_t h0f[2][4][512];   // [buf][kf][(qq*16+row)*8+jc]; rows 8-15 stay 0
    __shared__ ushort_t h1f[2][4][512];
    __shared__ ushort_t xf[2][512];       // rows 8-15 + k>=16 stay 0
    __shared__ uint4 fw1l[1024];          // fW1 frags (decoder FC)

    const int t = threadIdx.x;
    const int L = t & 63, w = t >> 6;
    const int col16 = L & 15, q = L >> 4;
    const int col = w * 16 + col16;
    const int b0 = blockIdx.x * BT;
    const bool wlo = (w < 4);             // SIMD-mates (w, w+4) get opposite order

    for (int i = t; i < 4096; i += NT) {
        (&h0f[0][0][0])[i] = 0;
        (&h1f[0][0][0])[i] = 0;
    }
    for (int i = t; i < 1024; i += NT) (&xf[0][0])[i] = 0;

    // write offset for the spread layout: rows (q&1)*4 + hi2 + e, e at +8
    const int kfc = col >> 5, qq = (col >> 3) & 3, jc = col & 7;
    const int hi2 = (L >> 5) * 2;
    const int hwoE = kfc * 512 + (qq * 16 + (q & 1) * 4 + hi2) * 8 + jc;

    const int xr = t >> 4, xfeat = t & 15;                 // xr in [0,8) for t<128
    const int xscat = (((xfeat >> 3) * 16) + (xr & 15)) * 8 + (xfeat & 7);
    float xv = (t < 128) ? x[((b0 + xr) * TIN + 0) * NFE + xfeat] : 0.f;

    // encoder per-lane bias scalars, PRE-SCALED
    const float e0_rz = SC_RZ * (ebih0[col] + ebhh0[col]);
    const float e0_zz = SC_RZ * (ebih0[HD + col] + ebhh0[HD + col]);
    const float e0_in = SC_N * ebih0[2 * HD + col];
    const float e0_hn = SC_N * ebhh0[2 * HD + col];
    const float e1_rz = SC_RZ * (ebih1[col] + ebhh1[col]);
    const float e1_zz = SC_RZ * (ebih1[HD + col] + ebhh1[HD + col]);
    const float e1_in = SC_N * ebih1[2 * HD + col];
    const float e1_hn = SC_N * ebhh1[2 * HD + col];

    float h0r[2] = {0, 0};
    float h1r[2] = {0, 0};

    // encoder weights -> registers
    short8 Wa[3][4], Wb[3][4], Wc[3][4];
    short8 We[3];
    #pragma unroll
    for (int t3 = 0; t3 < 3; ++t3) {
        const int nt = w + t3 * 8;
        We[t3] = wf[OFF_EWIH0 + nt * 64 + L];
        #pragma unroll
        for (int kf = 0; kf < 4; ++kf) {
            Wa[t3][kf] = wf[OFF_EWHH0 + (nt * 4 + kf) * 64 + L];
            Wb[t3][kf] = wf[OFF_EWIH1 + (nt * 4 + kf) * 64 + L];
            Wc[t3][kf] = wf[OFF_EWHH1 + (nt * 4 + kf) * 64 + L];
        }
    }

    barrier_lds();
    if (t < 128) {
        (&xf[0][0])[xscat] = f2bf_h(xv);                  // x(0)
        xv = x[((b0 + xr) * TIN + 1) * NFE + xfeat];
    }
    barrier_lds();

    // ---------------- encoder, pipelined: iter i = L0(i) + L1(i-1) ----------
    {
        if (t < 128) {
            (&xf[0][0])[512 + xscat] = f2bf_h(xv);        // x(1) -> xf[1]
            xv = x[((b0 + xr) * TIN + 2) * NFE + xfeat];
        }
        const short8 Ax = *(const short8*)&xf[0][L * 8];
        short8 Ah[4];
        #pragma unroll
        for (int kf = 0; kf < 4; ++kf)
            Ah[kf] = *(const short8*)&h0f[0][kf][L * 8];
        f32x4 gr = splat4(e0_rz), gz = splat4(e0_zz);
        f32x4 gni = splat4(e0_in), gnh = splat4(e0_hn);
        __builtin_amdgcn_s_setprio(1);
        #pragma unroll
        for (int kf = 0; kf < 4; ++kf) {
            gr  = __builtin_amdgcn_mfma_f32_16x16x32_bf16(Ah[kf], Wa[0][kf], gr,  0, 0, 0);
            gz  = __builtin_amdgcn_mfma_f32_16x16x32_bf16(Ah[kf], Wa[1][kf], gz,  0, 0, 0);
            gnh = __builtin_amdgcn_mfma_f32_16x16x32_bf16(Ah[kf], Wa[2][kf], gnh, 0, 0, 0);
        }
        gr  = __builtin_amdgcn_mfma_f32_16x16x32_bf16(Ax, We[0], gr,  0, 0, 0);
        gz  = __builtin_amdgcn_mfma_f32_16x16x32_bf16(Ax, We[1], gz,  0, 0, 0);
        gni = __builtin_amdgcn_mfma_f32_16x16x32_bf16(Ax, We[2], gni, 0, 0, 0);
        __builtin_amdgcn_s_setprio(0);
        combineS(gr, gz, gni, gnh, h0r, &(&h0f[0][0][0])[2048 + hwoE]);
        barrier_lds();
    }

    for (int i = 1; i < TIN; ++i) {
        const int p = i & 1;
        if (t < 128 && i + 1 < TIN) {
            (&xf[0][0])[(1 - p) * 512 + xscat] = f2bf_h(xv);
            if (i + 2 < TIN) xv = x[((b0 + xr) * TIN + i + 2) * NFE + xfeat];
        }
        const short8 Ax = *(const short8*)&xf[p][L * 8];
        short8 Ah0[4], Ah1[4];
        #pragma unroll
        for (int kf = 0; kf < 4; ++kf) {
            Ah0[kf] = *(const short8*)&h0f[p][kf][L * 8];  // h0(i-1)
            Ah1[kf] = *(const short8*)&h1f[p][kf][L * 8];  // h1(i-2)
        }
        f32x4 a_r, a_z, a_ni, a_nh;   // L0 gates
        f32x4 b_r, b_z, b_ni, b_nh;   // L1 gates

        auto doA = [&]() {            // L0(i): 15 MFMA
            a_r = splat4(e0_rz); a_z = splat4(e0_zz);
            a_ni = splat4(e0_in); a_nh = splat4(e0_hn);
            __builtin_amdgcn_s_setprio(1);
            #pragma unroll
            for (int kf = 0; kf < 4; ++kf) {
                a_r  = __builtin_amdgcn_mfma_f32_16x16x32_bf16(Ah0[kf], Wa[0][kf], a_r,  0, 0, 0);
                a_z  = __builtin_amdgcn_mfma_f32_16x16x32_bf16(Ah0[kf], Wa[1][kf], a_z,  0, 0, 0);
                a_nh = __builtin_amdgcn_mfma_f32_16x16x32_bf16(Ah0[kf], Wa[2][kf], a_nh, 0, 0, 0);
            }
            a_r  = __builtin_amdgcn_mfma_f32_16x16x32_bf16(Ax, We[0], a_r,  0, 0, 0);
            a_z  = __builtin_amdgcn_mfma_f32_16x16x32_bf16(Ax, We[1], a_z,  0, 0, 0);
            a_ni = __builtin_amdgcn_mfma_f32_16x16x32_bf16(Ax, We[2], a_ni, 0, 0, 0);
            __builtin_amdgcn_s_setprio(0);
        };
        auto doB = [&]() {            // L1(i-1): 24 MFMA
            b_r = splat4(e1_rz); b_z = splat4(e1_zz);
            b_ni = splat4(e1_in); b_nh = splat4(e1_hn);
            __builtin_amdgcn_s_setprio(1);
            #pragma unroll
            for (int kf = 0; kf < 4; ++kf) {
                b_r  = __builtin_amdgcn_mfma_f32_16x16x32_bf16(Ah0[kf], Wb[0][kf], b_r,  0, 0, 0);
                b_z  = __builtin_amdgcn_mfma_f32_16x16x32_bf16(Ah0[kf], Wb[1][kf], b_z,  0, 0, 0);
                b_ni = __builtin_amdgcn_mfma_f32_16x16x32_bf16(Ah0[kf], Wb[2][kf], b_ni, 0, 0, 0);
                b_r  = __builtin_amdgcn_mfma_f32_16x16x32_bf16(Ah1[kf], Wc[0][kf], b_r,  0, 0, 0);
                b_z  = __builtin_amdgcn_mfma_f32_16x16x32_bf16(Ah1[kf], Wc[1][kf], b_z,  0, 0, 0);
                b_nh = __builtin_amdgcn_mfma_f32_16x16x32_bf16(Ah1[kf], Wc[2][kf], b_nh, 0, 0, 0);
            }
            __builtin_amdgcn_s_setprio(0);
        };
        auto doCA = [&]() {
            combineS(a_r, a_z, a_ni, a_nh, h0r, &(&h0f[0][0][0])[(1 - p) * 2048 + hwoE]);
        };
        auto doCB = [&]() {
            combineS(b_r, b_z, b_ni, b_nh, h1r, &(&h1f[0][0][0])[(1 - p) * 2048 + hwoE]);
        };

        if (wlo) { doA(); doB(); doCA(); doCB(); }
        else     { doB(); doA(); doCB(); doCA(); }
        barrier_lds();
    }

    // epilogue: L1(335).  h0(335) in h0f[0], h1(334) in h1f[0].
    {
        short8 Ai[4], Ah[4];
        #pragma unroll
        for (int kf = 0; kf < 4; ++kf) {
            Ai[kf] = *(const short8*)&h0f[0][kf][L * 8];
            Ah[kf] = *(const short8*)&h1f[0][kf][L * 8];
        }
        f32x4 gr = splat4(e1_rz), gz = splat4(e1_zz);
        f32x4 gni = splat4(e1_in), gnh = splat4(e1_hn);
        __builtin_amdgcn_s_setprio(1);
        #pragma unroll
        for (int kf = 0; kf < 4; ++kf) {
            gr  = __builtin_amdgcn_mfma_f32_16x16x32_bf16(Ai[kf], Wb[0][kf], gr,  0, 0, 0);
            gz  = __builtin_amdgcn_mfma_f32_16x16x32_bf16(Ai[kf], Wb[1][kf], gz,  0, 0, 0);
            gni = __builtin_amdgcn_mfma_f32_16x16x32_bf16(Ai[kf], Wb[2][kf], gni, 0, 0, 0);
            gr  = __builtin_amdgcn_mfma_f32_16x16x32_bf16(Ah[kf], Wc[0][kf], gr,  0, 0, 0);
            gz  = __builtin_amdgcn_mfma_f32_16x16x32_bf16(Ah[kf], Wc[1][kf], gz,  0, 0, 0);
            gnh = __builtin_amdgcn_mfma_f32_16x16x32_bf16(Ah[kf], Wc[2][kf], gnh, 0, 0, 0);
        }
        __builtin_amdgcn_s_setprio(0);
        combineS(gr, gz, gni, gnh, h1r, &(&h1f[0][0][0])[2048 + hwoE]);  // h1(-1) -> h1f[1]
        barrier_lds();
    }

    asm volatile("" ::: "memory");

    // ---- decoder prologue: weights, fW1->LDS, biases, ghA(0), h0(0) --------
    #pragma unroll
    for (int t3 = 0; t3 < 3; ++t3) {
        const int nt = w + t3 * 8;
        #pragma unroll
        for (int kf = 0; kf < 4; ++kf) {
            Wa[t3][kf] = wf[OFF_DWHH0 + (nt * 4 + kf) * 64 + L];
            Wb[t3][kf] = wf[OFF_DWIH1 + (nt * 4 + kf) * 64 + L];
            Wc[t3][kf] = wf[OFF_DWHH1 + (nt * 4 + kf) * 64 + L];
        }
    }
    for (int i = t; i < 1024; i += NT) fw1l[i] = ((const uint4*)wf)[OFF_FW1 + i];

    const float d0_rz = SC_RZ * (dbih0[col] + dbhh0[col]);
    const float d0_zz = SC_RZ * (dbih0[HD + col] + dbhh0[HD + col]);
    const float d0_in = SC_N * dbih0[2 * HD + col];
    const float d0_hn = SC_N * dbhh0[2 * HD + col];
    const float d1_rz = SC_RZ * (dbih1[col] + dbhh1[col]);
    const float d1_zz = SC_RZ * (dbih1[HD + col] + dbhh1[HD + col]);
    const float d1_in = SC_N * dbih1[2 * HD + col];
    const float d1_hn = SC_N * dbhh1[2 * HD + col];
    const float w0r = SC_RZ * dWih0[col];
    const float w0z = SC_RZ * dWih0[HD + col];
    const float w0n = SC_N * dWih0[2 * HD + col];
    float f1bv[4], w2v[4];
    #pragma unroll
    for (int nt = 0; nt < 4; ++nt) {
        f1bv[nt] = fb1[nt * 16 + col16];
        w2v[nt]  = fW2[nt * 16 + col16];
    }
    const float fb2v = fb2[0];
    float ivr[2] = {0.f, 0.f};

    // prologue: ghA from h0_enc, then combine h0(0) (inp(-1)=0) -> h0f[0]
    {
        short8 Ah[4];
        #pragma unroll
        for (int kf = 0; kf < 4; ++kf)
            Ah[kf] = *(const short8*)&h0f[0][kf][L * 8];
        f32x4 g0 = splat4(d0_rz), g1 = splat4(d0_zz), g2 = splat4(d0_hn);
        __builtin_amdgcn_s_setprio(1);
        #pragma unroll
        for (int kf = 0; kf < 4; ++kf) {
            g0 = __builtin_amdgcn_mfma_f32_16x16x32_bf16(Ah[kf], Wa[0][kf], g0, 0, 0, 0);
            g1 = __builtin_amdgcn_mfma_f32_16x16x32_bf16(Ah[kf], Wa[1][kf], g1, 0, 0, 0);
            g2 = __builtin_amdgcn_mfma_f32_16x16x32_bf16(Ah[kf], Wa[2][kf], g2, 0, 0, 0);
        }
        __builtin_amdgcn_s_setprio(0);
        float g0e[2], g1e[2], g2e[2];
        spread2(g0, g0e[0], g0e[1]);
        spread2(g1, g1e[0], g1e[1]);
        spread2(g2, g2e[0], g2e[1]);
        barrier_lds();   // everyone done reading h0f[0] before overwrite
        ushort_t* wb = &(&h0f[0][0][0])[0 + hwoE];
        #pragma unroll
        for (int e = 0; e < 2; ++e) {
            const float rg = sig2(g0e[e]);
            const float zg = sig2(g1e[e]);
            const float ng = fmaf(2.f, sig2(d0_in + rg * g2e[e]), -1.f);
            const float hn = fmaf(zg, h0r[e] - ng, ng);
            h0r[e] = hn;
            wb[e * 8] = f2bf_h(hn);
        }
    }
    barrier_lds();

    // ---------------- decoder: 2 balanced phases/step ----------------------
    // h0(s) in h0f[s&1]; h1(s) in h1f[s&1] (h1(-1) in h1f[1]).
    for (int s = 0; s < TOUT; ++s) {
        const int p = s & 1;

        // ----- P2(s): L1(s) only (24 MFMA) ---------------------------------
        {
            short8 Ai[4], Ah[4];
            #pragma unroll
            for (int kf = 0; kf < 4; ++kf) {
                Ai[kf] = *(const short8*)&h0f[p][kf][L * 8];      // h0(s)
                Ah[kf] = *(const short8*)&h1f[1 - p][kf][L * 8];  // h1(s-1)
            }
            f32x4 gr = splat4(d1_rz), gz = splat4(d1_zz);
            f32x4 gni = splat4(d1_in), gnh = splat4(d1_hn);
            __builtin_amdgcn_s_setprio(1);
            #pragma unroll
            for (int kf = 0; kf < 4; ++kf) {
                gr  = __builtin_amdgcn_mfma_f32_16x16x32_bf16(Ai[kf], Wb[0][kf], gr,  0, 0, 0);
                gz  = __builtin_amdgcn_mfma_f32_16x16x32_bf16(Ai[kf], Wb[1][kf], gz,  0, 0, 0);
                gni = __builtin_amdgcn_mfma_f32_16x16x32_bf16(Ai[kf], Wb[2][kf], gni, 0, 0, 0);
                gr  = __builtin_amdgcn_mfma_f32_16x16x32_bf16(Ah[kf], Wc[0][kf], gr,  0, 0, 0);
                gz  = __builtin_amdgcn_mfma_f32_16x16x32_bf16(Ah[kf], Wc[1][kf], gz,  0, 0, 0);
                gnh = __builtin_amdgcn_mfma_f32_16x16x32_bf16(Ah[kf], Wc[2][kf], gnh, 0, 0, 0);
            }
            __builtin_amdgcn_s_setprio(0);
            combineS(gr, gz, gni, gnh, h1r, &(&h1f[0][0][0])[p * 2048 + hwoE]);  // h1(s)
        }
        barrier_lds();

        // ----- P1: FC(s) + ghA(s+1) + combine h0(s+1) (16+12 MFMA) ---------
        {
            short8 Af[4], Ah[4];
            #pragma unroll
            for (int kf = 0; kf < 4; ++kf) {
                Af[kf] = *(const short8*)&h1f[p][kf][L * 8];      // h1(s)
                Ah[kf] = *(const short8*)&h0f[p][kf][L * 8];      // h0(s)
            }
            f32x4 g0, g1, g2;
            f32x4 fc[4];

            auto doG = [&]() {        // ghA(s+1) = dWhh0 . h0(s), 12 MFMA
                g0 = splat4(d0_rz); g1 = splat4(d0_zz); g2 = splat4(d0_hn);
                __builtin_amdgcn_s_setprio(1);
                #pragma unroll
                for (int kf = 0; kf < 4; ++kf) {
                    g0 = __builtin_amdgcn_mfma_f32_16x16x32_bf16(Ah[kf], Wa[0][kf], g0, 0, 0, 0);
                    g1 = __builtin_amdgcn_mfma_f32_16x16x32_bf16(Ah[kf], Wa[1][kf], g1, 0, 0, 0);
                    g2 = __builtin_amdgcn_mfma_f32_16x16x32_bf16(Ah[kf], Wa[2][kf], g2, 0, 0, 0);
                }
                __builtin_amdgcn_s_setprio(0);
            };
            auto doF = [&]() {        // FC1: 16 MFMA
                #pragma unroll
                for (int nt = 0; nt < 4; ++nt) fc[nt] = splat4(0.f);
                __builtin_amdgcn_s_setprio(1);
                #pragma unroll
                for (int kf = 0; kf < 4; ++kf) {
                    #pragma unroll
                    for (int nt = 0; nt < 4; ++nt) {
                        const short8 b = *(const short8*)&fw1l[(nt * 4 + kf) * 64 + L];
                        fc[nt] = __builtin_amdgcn_mfma_f32_16x16x32_bf16(Af[kf], b, fc[nt], 0, 0, 0);
                    }
                }
                __builtin_amdgcn_s_setprio(0);
            };
            if (wlo) { doG(); doF(); }
            else     { doF(); doG(); }

            float g0e[2], g1e[2], g2e[2], fe0[4], fe1[4];
            #pragma unroll
            for (int nt = 0; nt < 4; ++nt) spread2(fc[nt], fe0[nt], fe1[nt]);
            float ps[2];
            #pragma unroll
            for (int e = 0; e < 2; ++e) {
                float s_ = 0.f;
                #pragma unroll
                for (int nt = 0; nt < 4; ++nt) {
                    const float v = (e == 0) ? fe0[nt] : fe1[nt];
                    s_ = fmaf(fmaxf(v + f1bv[nt], 0.f), w2v[nt], s_);
                }
                ps[e] = s_;
            }
            #pragma unroll
            for (int e = 0; e < 2; ++e) {
                ps[e] = sum16(ps[e]);                      // DPP 16-lane-group sum
                ivr[e] = fmaxf(ps[e] + fb2v, 0.f);
            }
            spread2(g0, g0e[0], g0e[1]);
            spread2(g1, g1e[0], g1e[1]);
            spread2(g2, g2e[0], g2e[1]);
            if (w == 0 && col16 == 0) {                    // lanes 0,16,32,48
                #pragma unroll
                for (int e = 0; e < 2; ++e)
                    out[(b0 + (q & 1) * 4 + hi2 + e) * TOUT + s] = ivr[e];
            }
            // combine h0(s+1) -> h0f[1-p]
            ushort_t* wb = &(&h0f[0][0][0])[(1 - p) * 2048 + hwoE];
            #pragma unroll
            for (int e = 0; e < 2; ++e) {
                const float iv = ivr[e];
                const float rg = sig2(fmaf(iv, w0r, g0e[e]));
                const float zg = sig2(fmaf(iv, w0z, g1e[e]));
                const float tt = fmaf(iv, w0n, d0_in) + rg * g2e[e];
                const float ng = fmaf(2.f, sig2(tt), -1.f);
                const float hn = fmaf(zg, h0r[e] - ng, ng);
                h0r[e] = hn;
                wb[e * 8] = f2bf_h(hn);
            }
        }
        barrier_lds();
    }
}

extern "C" void kernel_launch(void* const* d_in, const int* in_sizes, int n_in,
                              void* d_out, int out_size, void* d_ws, size_t ws_size,
                              hipStream_t stream) {
    const float* x     = (const float*)d_in[0];
    const float* eWih0 = (const float*)d_in[1];
    const float* eWhh0 = (const float*)d_in[2];
    const float* ebih0 = (const float*)d_in[3];
    const float* ebhh0 = (const float*)d_in[4];
    const float* eWih1 = (const float*)d_in[5];
    const float* eWhh1 = (const float*)d_in[6];
    const float* ebih1 = (const float*)d_in[7];
    const float* ebhh1 = (const float*)d_in[8];
    const float* dWih0 = (const float*)d_in[9];
    const float* dWhh0 = (const float*)d_in[10];
    const float* dbih0 = (const float*)d_in[11];
    const float* dbhh0 = (const float*)d_in[12];
    const float* dWih1 = (const float*)d_in[13];
    const float* dWhh1 = (const float*)d_in[14];
    const float* dbih1 = (const float*)d_in[15];
    const float* dbhh1 = (const float*)d_in[16];
    const float* fW1   = (const float*)d_in[17];
    const float* fb1   = (const float*)d_in[18];
    const float* fW2   = (const float*)d_in[19];
    const float* fb2   = (const float*)d_in[20];
    float* out = (float*)d_out;

    hipLaunchKernelGGL(prep_kernel, dim3(616), dim3(64), 0, stream,
                       eWhh0, eWih1, eWhh1, dWhh0, dWih1, dWhh1, eWih0, fW1,
                       (uint4*)d_ws);
    hipLaunchKernelGGL(gru_seq2seq_kernel, dim3(NB), dim3(NT), 0, stream,
                       x, ebih0, ebhh0, ebih1, ebhh1,
                       dWih0, dbih0, dbhh0, dbih1, dbhh1,
                       fb1, fW2, fb2,
                       (const short8*)d_ws, out);
}

// Round 4
// 832.566 us; speedup vs baseline: 1.0063x; 1.0063x over previous
//
#include <hip/hip_runtime.h>

// GRU seq2seq, MI355X gfx950. Round 14: R11 base + encoder-only SGB ladder
//   + DPP sum16 decoder FC-reduce.
//   R11: MfmaUtil 44 + VALUBusy 49 ~= 100% -> per-phase [39 MFMA][combine]
//   serialize (lockstep waves, in-order issue). R12 branch-skew spilled.
//   R13 (3 SGB ladders incl. decoder) -> container failed; this round keeps
//   ONE SGB ladder in the encoder steady loop only (337 heavy phases):
//   {9 ds_read, 36 VALU, then 13 x {3 MFMA, 8 VALU}} so the a-chain combine
//   VALU overlaps the b-chain MFMA stream. Decoder unchanged from R11 except
//   sum16 (DPP quad_perm/row_ror adds) replacing 8 serial ds_bpermute
//   shuffles on the h0-feedback critical path.
//   Structure: 256 blocks x BT=8, spread-2 combine (permlane32_swap),
//   register/AGPR-resident weights, 1-barrier encoder, 2-phase decoder.

typedef unsigned short ushort_t;
typedef unsigned int uint_t;
typedef __attribute__((ext_vector_type(8))) short short8;
typedef __attribute__((ext_vector_type(4))) float f32x4;
typedef __attribute__((ext_vector_type(2))) unsigned int uintx2;

#define BT   8
#define NT   512
#define HD   128
#define TIN  336
#define TOUT 168
#define NFE  16
#define NB   256

#define SC_RZ (-1.44269504089f)   // -log2(e)
#define SC_N  (-2.88539008177f)   // -2*log2(e)

#define OFF_EWHH0 0
#define OFF_EWIH1 6144
#define OFF_EWHH1 12288
#define OFF_DWHH0 18432
#define OFF_DWIH1 24576
#define OFF_DWHH1 30720
#define OFF_EWIH0 36864
#define OFF_FW1   38400

// sched_group_barrier masks (LLVM SchedGroupMask)
#define SGB_VALU 0x002
#define SGB_MFMA 0x008
#define SGB_DSRD 0x100
#define SGB(m, n) __builtin_amdgcn_sched_group_barrier((m), (n), 0)

__device__ __forceinline__ ushort_t f2bf(float f) {      // RNE (prep only)
    union { float f; uint_t u; } v; v.f = f;
    uint_t r = v.u + 0x7FFFu + ((v.u >> 16) & 1u);
    return (ushort_t)(r >> 16);
}
__device__ __forceinline__ ushort_t f2bf_h(float f) {    // round-half-up, 2 VALU
    union { float f; uint_t u; } v; v.f = f;
    return (ushort_t)((v.u + 0x8000u) >> 16);
}
__device__ __forceinline__ f32x4 splat4(float v) {
    return (f32x4){v, v, v, v};
}
__device__ __forceinline__ float sig2(float t) {         // sigmoid of pre-scaled acc
    return __builtin_amdgcn_rcpf(1.f + __builtin_amdgcn_exp2f(t));
}
__device__ __forceinline__ void barrier_lds() {
    asm volatile("s_waitcnt lgkmcnt(0)\n\ts_barrier" ::: "memory");
}

// a' = [a.lo | b.lo], b' = [a.hi | b.hi]
__device__ __forceinline__ void pl32swap(float& a, float& b) {
    uintx2 r = __builtin_amdgcn_permlane32_swap(
        __float_as_uint(a), __float_as_uint(b), false, false);
    a = __uint_as_float(r[0]);
    b = __uint_as_float(r[1]);
}
// Pack the 8 valid C-rows (rows 0-7, lanes q=0,1) across all 64 lanes.
__device__ __forceinline__ void spread2(f32x4 v, float& e0, float& e1) {
    float a0 = v[0], a2 = v[2];
    float a1 = v[1], a3 = v[3];
    pl32swap(a0, a2);
    pl32swap(a1, a3);
    e0 = a0; e1 = a1;
}

// ---- DPP 16-lane-group sum: every lane gets the sum of its 16-lane row ----
template <int CTRL>
__device__ __forceinline__ float dpp_add(float acc) {
    int x = __builtin_amdgcn_update_dpp(0, __float_as_int(acc), CTRL, 0xF, 0xF, true);
    return acc + __int_as_float(x);
}
__device__ __forceinline__ float sum16(float v) {
    v = dpp_add<0xB1>(v);    // quad_perm [1,0,3,2]  (xor 1)
    v = dpp_add<0x4E>(v);    // quad_perm [2,3,0,1]  (xor 2)
    v = dpp_add<0x124>(v);   // row_ror:4  (quad-pair)
    v = dpp_add<0x128>(v);   // row_ror:8  (opposite pair)
    return v;
}

// ---------------- prep: fp32 weights -> bf16 MFMA B-fragments ----------------
// Gate matrices PRE-SCALED: rows [0,256) by -log2e, rows [256,384) by -2log2e.
extern "C" __global__ __launch_bounds__(64)
void prep_kernel(const float* __restrict__ eWhh0, const float* __restrict__ eWih1,
                 const float* __restrict__ eWhh1, const float* __restrict__ dWhh0,
                 const float* __restrict__ dWih1, const float* __restrict__ dWhh1,
                 const float* __restrict__ eWih0, const float* __restrict__ fW1,
                 uint4* __restrict__ ws)
{
    const int g = blockIdx.x;
    const int L = threadIdx.x;
    const int n_lo = L & 15, q = L >> 4;

    const float* src; int n, kb, Ksrc, dst16; float sc;
    if (g < 576) {
        const int m = g / 96, lf = g % 96;
        const float* hs[6] = {eWhh0, eWih1, eWhh1, dWhh0, dWih1, dWhh1};
        src = hs[m];
        const int nt = lf >> 2, kf = lf & 3;
        n = nt * 16 + n_lo; kb = kf * 32 + q * 8; Ksrc = 128;
        dst16 = m * 6144 + lf * 64 + L;
        sc = (n < 2 * HD) ? SC_RZ : SC_N;
    } else if (g < 600) {
        const int nt = g - 576;
        src = eWih0; n = nt * 16 + n_lo; kb = q * 8; Ksrc = 16;
        dst16 = OFF_EWIH0 + nt * 64 + L;
        sc = (n < 2 * HD) ? SC_RZ : SC_N;
    } else {
        const int lf = g - 600;
        src = fW1; n = (lf >> 2) * 16 + n_lo; kb = (lf & 3) * 32 + q * 8; Ksrc = 128;
        dst16 = OFF_FW1 + lf * 64 + L;
        sc = 1.f;
    }

    ushort_t h[8];
    #pragma unroll
    for (int j = 0; j < 8; ++j) {
        const int k = kb + j;
        h[j] = (k < Ksrc) ? f2bf(sc * src[n * Ksrc + k]) : (ushort_t)0;
    }
    uint4 o;
    o.x = (uint_t)h[0] | ((uint_t)h[1] << 16);
    o.y = (uint_t)h[2] | ((uint_t)h[3] << 16);
    o.z = (uint_t)h[4] | ((uint_t)h[5] << 16);
    o.w = (uint_t)h[6] | ((uint_t)h[7] << 16);
    ws[dst16] = o;
}

// Spread-combine: 2 valid elements per lane (rows (q&1)*4 + hi2 + e).
__device__ __forceinline__ void combineS(const f32x4& gr, const f32x4& gz,
                                         const f32x4& gn_i, const f32x4& gn_h,
                                         float* hreg, ushort_t* wb)
{
    float r_[2], z_[2], i_[2], n_[2];
    spread2(gr,   r_[0], r_[1]);
    spread2(gz,   z_[0], z_[1]);
    spread2(gn_i, i_[0], i_[1]);
    spread2(gn_h, n_[0], n_[1]);
    #pragma unroll
    for (int e = 0; e < 2; ++e) {
        const float rg = sig2(r_[e]);
        const float zg = sig2(z_[e]);
        const float ng = fmaf(2.f, sig2(i_[e] + rg * n_[e]), -1.f);
        const float hn = fmaf(zg, hreg[e] - ng, ng);
        hreg[e] = hn;
        wb[e * 8] = f2bf_h(hn);
    }
}

extern "C" __global__ __launch_bounds__(NT, 2)
void gru_seq2seq_kernel(
    const float* __restrict__ x,
    const float* __restrict__ ebih0, const float* __restrict__ ebhh0,
    const float* __restrict__ ebih1, const float* __restrict__ ebhh1,
    const float* __restrict__ dWih0, const float* __restrict__ dbih0,
    const float* __restrict__ dbhh0,
    const float* __restrict__ dbih1, const float* __restrict__ dbhh1,
    const float* __restrict__ fb1, const float* __restrict__ fW2,
    const float* __restrict__ fb2,
    const short8* __restrict__ wf,
    float* __restrict__ out)
{
    __shared__ ushort_t h0f[2][4][512];   // [buf][kf][(qq*16+row)*8+jc]; rows 8-15 stay 0
    __shared__ ushort_t h1f[2][4][512];
    __shared__ ushort_t xf[2][512];       // rows 8-15 + k>=16 stay 0
    __shared__ uint4 fw1l[1024];          // fW1 frags (decoder FC)

    const int t = threadIdx.x;
    const int L = t & 63, w = t >> 6;
    const int col16 = L & 15, q = L >> 4;
    const int col = w * 16 + col16;
    const int b0 = blockIdx.x * BT;

    for (int i = t; i < 4096; i += NT) {
        (&h0f[0][0][0])[i] = 0;
        (&h1f[0][0][0])[i] = 0;
    }
    for (int i = t; i < 1024; i += NT) (&xf[0][0])[i] = 0;

    // write offset for the spread layout: rows (q&1)*4 + hi2 + e, e at +8
    const int kfc = col >> 5, qq = (col >> 3) & 3, jc = col & 7;
    const int hi2 = (L >> 5) * 2;
    const int hwoE = kfc * 512 + (qq * 16 + (q & 1) * 4 + hi2) * 8 + jc;

    const int xr = t >> 4, xfeat = t & 15;                 // xr in [0,8) for t<128
    const int xscat = (((xfeat >> 3) * 16) + (xr & 15)) * 8 + (xfeat & 7);
    float xv = (t < 128) ? x[((b0 + xr) * TIN + 0) * NFE + xfeat] : 0.f;

    // encoder per-lane bias scalars, PRE-SCALED
    const float e0_rz = SC_RZ * (ebih0[col] + ebhh0[col]);
    const float e0_zz = SC_RZ * (ebih0[HD + col] + ebhh0[HD + col]);
    const float e0_in = SC_N * ebih0[2 * HD + col];
    const float e0_hn = SC_N * ebhh0[2 * HD + col];
    const float e1_rz = SC_RZ * (ebih1[col] + ebhh1[col]);
    const float e1_zz = SC_RZ * (ebih1[HD + col] + ebhh1[HD + col]);
    const float e1_in = SC_N * ebih1[2 * HD + col];
    const float e1_hn = SC_N * ebhh1[2 * HD + col];

    float h0r[2] = {0, 0};
    float h1r[2] = {0, 0};

    // encoder weights -> registers
    short8 Wa[3][4], Wb[3][4], Wc[3][4];
    short8 We[3];
    #pragma unroll
    for (int t3 = 0; t3 < 3; ++t3) {
        const int nt = w + t3 * 8;
        We[t3] = wf[OFF_EWIH0 + nt * 64 + L];
        #pragma unroll
        for (int kf = 0; kf < 4; ++kf) {
            Wa[t3][kf] = wf[OFF_EWHH0 + (nt * 4 + kf) * 64 + L];
            Wb[t3][kf] = wf[OFF_EWIH1 + (nt * 4 + kf) * 64 + L];
            Wc[t3][kf] = wf[OFF_EWHH1 + (nt * 4 + kf) * 64 + L];
        }
    }

    barrier_lds();
    if (t < 128) {
        (&xf[0][0])[xscat] = f2bf_h(xv);                  // x(0)
        xv = x[((b0 + xr) * TIN + 1) * NFE + xfeat];
    }
    barrier_lds();

    // ---------------- encoder, pipelined: iter i = L0(i) + L1(i-1) ----------
    {
        if (t < 128) {
            (&xf[0][0])[512 + xscat] = f2bf_h(xv);        // x(1) -> xf[1]
            xv = x[((b0 + xr) * TIN + 2) * NFE + xfeat];
        }
        const short8 Ax = *(const short8*)&xf[0][L * 8];
        short8 Ah[4];
        #pragma unroll
        for (int kf = 0; kf < 4; ++kf)
            Ah[kf] = *(const short8*)&h0f[0][kf][L * 8];
        f32x4 gr = splat4(e0_rz), gz = splat4(e0_zz);
        f32x4 gni = splat4(e0_in), gnh = splat4(e0_hn);
        #pragma unroll
        for (int kf = 0; kf < 4; ++kf) {
            gr  = __builtin_amdgcn_mfma_f32_16x16x32_bf16(Ah[kf], Wa[0][kf], gr,  0, 0, 0);
            gz  = __builtin_amdgcn_mfma_f32_16x16x32_bf16(Ah[kf], Wa[1][kf], gz,  0, 0, 0);
            gnh = __builtin_amdgcn_mfma_f32_16x16x32_bf16(Ah[kf], Wa[2][kf], gnh, 0, 0, 0);
        }
        gr  = __builtin_amdgcn_mfma_f32_16x16x32_bf16(Ax, We[0], gr,  0, 0, 0);
        gz  = __builtin_amdgcn_mfma_f32_16x16x32_bf16(Ax, We[1], gz,  0, 0, 0);
        gni = __builtin_amdgcn_mfma_f32_16x16x32_bf16(Ax, We[2], gni, 0, 0, 0);
        combineS(gr, gz, gni, gnh, h0r, &(&h0f[0][0][0])[2048 + hwoE]);
        barrier_lds();
    }

    for (int i = 1; i < TIN; ++i) {
        const int p = i & 1;
        if (t < 128 && i + 1 < TIN) {
            (&xf[0][0])[(1 - p) * 512 + xscat] = f2bf_h(xv);
            if (i + 2 < TIN) xv = x[((b0 + xr) * TIN + i + 2) * NFE + xfeat];
        }
        const short8 Ax = *(const short8*)&xf[p][L * 8];
        short8 Ah0[4], Ah1[4];
        #pragma unroll
        for (int kf = 0; kf < 4; ++kf) {
            Ah0[kf] = *(const short8*)&h0f[p][kf][L * 8];  // h0(i-1)
            Ah1[kf] = *(const short8*)&h1f[p][kf][L * 8];  // h1(i-2)
        }
        f32x4 a_r = splat4(e0_rz), a_z = splat4(e0_zz);
        f32x4 a_ni = splat4(e0_in), a_nh = splat4(e0_hn);
        f32x4 b_r = splat4(e1_rz), b_z = splat4(e1_zz);
        f32x4 b_ni = splat4(e1_in), b_nh = splat4(e1_hn);
        #pragma unroll
        for (int kf = 0; kf < 4; ++kf) {
            a_r  = __builtin_amdgcn_mfma_f32_16x16x32_bf16(Ah0[kf], Wa[0][kf], a_r,  0, 0, 0);
            a_z  = __builtin_amdgcn_mfma_f32_16x16x32_bf16(Ah0[kf], Wa[1][kf], a_z,  0, 0, 0);
            a_nh = __builtin_amdgcn_mfma_f32_16x16x32_bf16(Ah0[kf], Wa[2][kf], a_nh, 0, 0, 0);
            b_r  = __builtin_amdgcn_mfma_f32_16x16x32_bf16(Ah0[kf], Wb[0][kf], b_r,  0, 0, 0);
            b_z  = __builtin_amdgcn_mfma_f32_16x16x32_bf16(Ah0[kf], Wb[1][kf], b_z,  0, 0, 0);
            b_ni = __builtin_amdgcn_mfma_f32_16x16x32_bf16(Ah0[kf], Wb[2][kf], b_ni, 0, 0, 0);
            b_r  = __builtin_amdgcn_mfma_f32_16x16x32_bf16(Ah1[kf], Wc[0][kf], b_r,  0, 0, 0);
            b_z  = __builtin_amdgcn_mfma_f32_16x16x32_bf16(Ah1[kf], Wc[1][kf], b_z,  0, 0, 0);
            b_nh = __builtin_amdgcn_mfma_f32_16x16x32_bf16(Ah1[kf], Wc[2][kf], b_nh, 0, 0, 0);
        }
        a_r  = __builtin_amdgcn_mfma_f32_16x16x32_bf16(Ax, We[0], a_r,  0, 0, 0);
        a_z  = __builtin_amdgcn_mfma_f32_16x16x32_bf16(Ax, We[1], a_z,  0, 0, 0);
        a_ni = __builtin_amdgcn_mfma_f32_16x16x32_bf16(Ax, We[2], a_ni, 0, 0, 0);

        combineS(a_r, a_z, a_ni, a_nh, h0r, &(&h0f[0][0][0])[(1 - p) * 2048 + hwoE]);
        combineS(b_r, b_z, b_ni, b_nh, h1r, &(&h1f[0][0][0])[(1 - p) * 2048 + hwoE]);

        // Single SGB ladder: ds_reads first, then interleave 3 MFMA / 8 VALU
        // so the a-chain combine (ready after MFMA 15) overlaps b-chain MFMAs.
        SGB(SGB_DSRD, 9);
        SGB(SGB_VALU, 36);
        #pragma unroll
        for (int u_ = 0; u_ < 13; ++u_) {
            SGB(SGB_MFMA, 3);
            SGB(SGB_VALU, 8);
        }
        barrier_lds();
    }

    // epilogue: L1(335).  h0(335) in h0f[0], h1(334) in h1f[0].
    {
        short8 Ai[4], Ah[4];
        #pragma unroll
        for (int kf = 0; kf < 4; ++kf) {
            Ai[kf] = *(const short8*)&h0f[0][kf][L * 8];
            Ah[kf] = *(const short8*)&h1f[0][kf][L * 8];
        }
        f32x4 gr = splat4(e1_rz), gz = splat4(e1_zz);
        f32x4 gni = splat4(e1_in), gnh = splat4(e1_hn);
        #pragma unroll
        for (int kf = 0; kf < 4; ++kf) {
            gr  = __builtin_amdgcn_mfma_f32_16x16x32_bf16(Ai[kf], Wb[0][kf], gr,  0, 0, 0);
            gz  = __builtin_amdgcn_mfma_f32_16x16x32_bf16(Ai[kf], Wb[1][kf], gz,  0, 0, 0);
            gni = __builtin_amdgcn_mfma_f32_16x16x32_bf16(Ai[kf], Wb[2][kf], gni, 0, 0, 0);
            gr  = __builtin_amdgcn_mfma_f32_16x16x32_bf16(Ah[kf], Wc[0][kf], gr,  0, 0, 0);
            gz  = __builtin_amdgcn_mfma_f32_16x16x32_bf16(Ah[kf], Wc[1][kf], gz,  0, 0, 0);
            gnh = __builtin_amdgcn_mfma_f32_16x16x32_bf16(Ah[kf], Wc[2][kf], gnh, 0, 0, 0);
        }
        combineS(gr, gz, gni, gnh, h1r, &(&h1f[0][0][0])[2048 + hwoE]);  // h1(-1) -> h1f[1]
        barrier_lds();
    }

    asm volatile("" ::: "memory");

    // ---- decoder prologue: weights, fW1->LDS, biases, ghA(0), h0(0) --------
    #pragma unroll
    for (int t3 = 0; t3 < 3; ++t3) {
        const int nt = w + t3 * 8;
        #pragma unroll
        for (int kf = 0; kf < 4; ++kf) {
            Wa[t3][kf] = wf[OFF_DWHH0 + (nt * 4 + kf) * 64 + L];
            Wb[t3][kf] = wf[OFF_DWIH1 + (nt * 4 + kf) * 64 + L];
            Wc[t3][kf] = wf[OFF_DWHH1 + (nt * 4 + kf) * 64 + L];
        }
    }
    for (int i = t; i < 1024; i += NT) fw1l[i] = ((const uint4*)wf)[OFF_FW1 + i];

    const float d0_rz = SC_RZ * (dbih0[col] + dbhh0[col]);
    const float d0_zz = SC_RZ * (dbih0[HD + col] + dbhh0[HD + col]);
    const float d0_in = SC_N * dbih0[2 * HD + col];
    const float d0_hn = SC_N * dbhh0[2 * HD + col];
    const float d1_rz = SC_RZ * (dbih1[col] + dbhh1[col]);
    const float d1_zz = SC_RZ * (dbih1[HD + col] + dbhh1[HD + col]);
    const float d1_in = SC_N * dbih1[2 * HD + col];
    const float d1_hn = SC_N * dbhh1[2 * HD + col];
    const float w0r = SC_RZ * dWih0[col];
    const float w0z = SC_RZ * dWih0[HD + col];
    const float w0n = SC_N * dWih0[2 * HD + col];
    float f1bv[4], w2v[4];
    #pragma unroll
    for (int nt = 0; nt < 4; ++nt) {
        f1bv[nt] = fb1[nt * 16 + col16];
        w2v[nt]  = fW2[nt * 16 + col16];
    }
    const float fb2v = fb2[0];
    float ivr[2] = {0.f, 0.f};

    // prologue: ghA from h0_enc, then combine h0(0) (inp(-1)=0) -> h0f[0]
    {
        short8 Ah[4];
        #pragma unroll
        for (int kf = 0; kf < 4; ++kf)
            Ah[kf] = *(const short8*)&h0f[0][kf][L * 8];
        f32x4 g0 = splat4(d0_rz), g1 = splat4(d0_zz), g2 = splat4(d0_hn);
        #pragma unroll
        for (int kf = 0; kf < 4; ++kf) {
            g0 = __builtin_amdgcn_mfma_f32_16x16x32_bf16(Ah[kf], Wa[0][kf], g0, 0, 0, 0);
            g1 = __builtin_amdgcn_mfma_f32_16x16x32_bf16(Ah[kf], Wa[1][kf], g1, 0, 0, 0);
            g2 = __builtin_amdgcn_mfma_f32_16x16x32_bf16(Ah[kf], Wa[2][kf], g2, 0, 0, 0);
        }
        float g0e[2], g1e[2], g2e[2];
        spread2(g0, g0e[0], g0e[1]);
        spread2(g1, g1e[0], g1e[1]);
        spread2(g2, g2e[0], g2e[1]);
        barrier_lds();   // everyone done reading h0f[0] before overwrite
        ushort_t* wb = &(&h0f[0][0][0])[0 + hwoE];
        #pragma unroll
        for (int e = 0; e < 2; ++e) {
            const float rg = sig2(g0e[e]);
            const float zg = sig2(g1e[e]);
            const float ng = fmaf(2.f, sig2(d0_in + rg * g2e[e]), -1.f);
            const float hn = fmaf(zg, h0r[e] - ng, ng);
            h0r[e] = hn;
            wb[e * 8] = f2bf_h(hn);
        }
    }
    barrier_lds();

    // ---------------- decoder: 2 balanced phases/step ----------------------
    // h0(s) in h0f[s&1]; h1(s) in h1f[s&1] (h1(-1) in h1f[1]).
    for (int s = 0; s < TOUT; ++s) {
        const int p = s & 1;

        // ----- P2(s): L1(s) only (24 MFMA) ---------------------------------
        {
            short8 Ai[4], Ah[4];
            #pragma unroll
            for (int kf = 0; kf < 4; ++kf) {
                Ai[kf] = *(const short8*)&h0f[p][kf][L * 8];      // h0(s)
                Ah[kf] = *(const short8*)&h1f[1 - p][kf][L * 8];  // h1(s-1)
            }
            f32x4 gr = splat4(d1_rz), gz = splat4(d1_zz);
            f32x4 gni = splat4(d1_in), gnh = splat4(d1_hn);
            #pragma unroll
            for (int kf = 0; kf < 4; ++kf) {
                gr  = __builtin_amdgcn_mfma_f32_16x16x32_bf16(Ai[kf], Wb[0][kf], gr,  0, 0, 0);
                gz  = __builtin_amdgcn_mfma_f32_16x16x32_bf16(Ai[kf], Wb[1][kf], gz,  0, 0, 0);
                gni = __builtin_amdgcn_mfma_f32_16x16x32_bf16(Ai[kf], Wb[2][kf], gni, 0, 0, 0);
                gr  = __builtin_amdgcn_mfma_f32_16x16x32_bf16(Ah[kf], Wc[0][kf], gr,  0, 0, 0);
                gz  = __builtin_amdgcn_mfma_f32_16x16x32_bf16(Ah[kf], Wc[1][kf], gz,  0, 0, 0);
                gnh = __builtin_amdgcn_mfma_f32_16x16x32_bf16(Ah[kf], Wc[2][kf], gnh, 0, 0, 0);
            }
            combineS(gr, gz, gni, gnh, h1r, &(&h1f[0][0][0])[p * 2048 + hwoE]);  // h1(s)
        }
        barrier_lds();

        // ----- P1: FC(s) + ghA(s+1) + combine h0(s+1) (16+12 MFMA) ---------
        {
            short8 Af[4], Ah[4];
            #pragma unroll
            for (int kf = 0; kf < 4; ++kf) {
                Af[kf] = *(const short8*)&h1f[p][kf][L * 8];      // h1(s)
                Ah[kf] = *(const short8*)&h0f[p][kf][L * 8];      // h0(s)
            }
            // ghA(s+1) = dWhh0 . h0(s), bias-init (consumed below, in-phase)
            f32x4 g0 = splat4(d0_rz), g1 = splat4(d0_zz), g2 = splat4(d0_hn);
            f32x4 fc[4];
            #pragma unroll
            for (int nt = 0; nt < 4; ++nt) fc[nt] = splat4(0.f);
            #pragma unroll
            for (int kf = 0; kf < 4; ++kf) {
                g0 = __builtin_amdgcn_mfma_f32_16x16x32_bf16(Ah[kf], Wa[0][kf], g0, 0, 0, 0);
                g1 = __builtin_amdgcn_mfma_f32_16x16x32_bf16(Ah[kf], Wa[1][kf], g1, 0, 0, 0);
                g2 = __builtin_amdgcn_mfma_f32_16x16x32_bf16(Ah[kf], Wa[2][kf], g2, 0, 0, 0);
                #pragma unroll
                for (int nt = 0; nt < 4; ++nt) {
                    const short8 b = *(const short8*)&fw1l[(nt * 4 + kf) * 64 + L];
                    fc[nt] = __builtin_amdgcn_mfma_f32_16x16x32_bf16(Af[kf], b, fc[nt], 0, 0, 0);
                }
            }
            float g0e[2], g1e[2], g2e[2], fe0[4], fe1[4];
            #pragma unroll
            for (int nt = 0; nt < 4; ++nt) spread2(fc[nt], fe0[nt], fe1[nt]);
            float ps[2];
            #pragma unroll
            for (int e = 0; e < 2; ++e) {
                float s_ = 0.f;
                #pragma unroll
                for (int nt = 0; nt < 4; ++nt) {
                    const float v = (e == 0) ? fe0[nt] : fe1[nt];
                    s_ = fmaf(fmaxf(v + f1bv[nt], 0.f), w2v[nt], s_);
                }
                ps[e] = s_;
            }
            #pragma unroll
            for (int e = 0; e < 2; ++e) {
                ps[e] = sum16(ps[e]);                      // DPP 16-lane-group sum
                ivr[e] = fmaxf(ps[e] + fb2v, 0.f);
            }
            spread2(g0, g0e[0], g0e[1]);
            spread2(g1, g1e[0], g1e[1]);
            spread2(g2, g2e[0], g2e[1]);
            if (w == 0 && col16 == 0) {                    // lanes 0,16,32,48
                #pragma unroll
                for (int e = 0; e < 2; ++e)
                    out[(b0 + (q & 1) * 4 + hi2 + e) * TOUT + s] = ivr[e];
            }
            // combine h0(s+1) -> h0f[1-p]
            ushort_t* wb = &(&h0f[0][0][0])[(1 - p) * 2048 + hwoE];
            #pragma unroll
            for (int e = 0; e < 2; ++e) {
                const float iv = ivr[e];
                const float rg = sig2(fmaf(iv, w0r, g0e[e]));
                const float zg = sig2(fmaf(iv, w0z, g1e[e]));
                const float tt = fmaf(iv, w0n, d0_in) + rg * g2e[e];
                const float ng = fmaf(2.f, sig2(tt), -1.f);
                const float hn = fmaf(zg, h0r[e] - ng, ng);
                h0r[e] = hn;
                wb[e * 8] = f2bf_h(hn);
            }
        }
        barrier_lds();
    }
}

extern "C" void kernel_launch(void* const* d_in, const int* in_sizes, int n_in,
                              void* d_out, int out_size, void* d_ws, size_t ws_size,
                              hipStream_t stream) {
    const float* x     = (const float*)d_in[0];
    const float* eWih0 = (const float*)d_in[1];
    const float* eWhh0 = (const float*)d_in[2];
    const float* ebih0 = (const float*)d_in[3];
    const float* ebhh0 = (const float*)d_in[4];
    const float* eWih1 = (const float*)d_in[5];
    const float* eWhh1 = (const float*)d_in[6];
    const float* ebih1 = (const float*)d_in[7];
    const float* ebhh1 = (const float*)d_in[8];
    const float* dWih0 = (const float*)d_in[9];
    const float* dWhh0 = (const float*)d_in[10];
    const float* dbih0 = (const float*)d_in[11];
    const float* dbhh0 = (const float*)d_in[12];
    const float* dWih1 = (const float*)d_in[13];
    const float* dWhh1 = (const float*)d_in[14];
    const float* dbih1 = (const float*)d_in[15];
    const float* dbhh1 = (const float*)d_in[16];
    const float* fW1   = (const float*)d_in[17];
    const float* fb1   = (const float*)d_in[18];
    const float* fW2   = (const float*)d_in[19];
    const float* fb2   = (const float*)d_in[20];
    float* out = (float*)d_out;

    hipLaunchKernelGGL(prep_kernel, dim3(616), dim3(64), 0, stream,
                       eWhh0, eWih1, eWhh1, dWhh0, dWih1, dWhh1, eWih0, fW1,
                       (uint4*)d_ws);
    hipLaunchKernelGGL(gru_seq2seq_kernel, dim3(NB), dim3(NT), 0, stream,
                       x, ebih0, ebhh0, ebih1, ebhh1,
                       dWih0, dbih0, dbhh0, dbih1, dbhh1,
                       fb1, fW2, fb2,
                       (const short8*)d_ws, out);
}

// Round 5
// 790.099 us; speedup vs baseline: 1.0604x; 1.0537x over previous
//
#include <hip/hip_runtime.h>

// GRU seq2seq, MI355X gfx950. Round 15: liveness-minimal wave-group skew.
//   Theory (unfalsified since R11): MfmaUtil 44 + VALUBusy 49 ~= 100% ->
//   lockstep waves serialize [39 MFMA][combine] per phase.
//   R12 ([aM][bM][cA][cB] skew, lambdas+setprio) and R14 (SGB ladder) both
//   DIED OF SPILLS (WRITE_SIZE 1.3->7.5/22 MB), never testing the overlap.
//   R15: arm-lo = [aM][cA][bM][cB], arm-hi = [bM][cB][aM][cA] - each combine
//   consumes its accs BEFORE the other MFMA block creates new ones, so peak
//   acc liveness is LOWER than R11's own tail. Full bodies per arm, locals
//   inside; only h0r/h1r/xv cross the join. No SGB, no setprio.
//   Overlap: lo's combine-VALU runs under hi's MFMA block and vice versa.
//   Decoder: R11 structure + DPP sum16 (validated in R14).
//   Structure: 256 blocks x BT=8, spread-2 combine (permlane32_swap),
//   register/AGPR-resident weights, 1-barrier encoder, 2-phase decoder.

typedef unsigned short ushort_t;
typedef unsigned int uint_t;
typedef __attribute__((ext_vector_type(8))) short short8;
typedef __attribute__((ext_vector_type(4))) float f32x4;
typedef __attribute__((ext_vector_type(2))) unsigned int uintx2;

#define BT   8
#define NT   512
#define HD   128
#define TIN  336
#define TOUT 168
#define NFE  16
#define NB   256

#define SC_RZ (-1.44269504089f)   // -log2(e)
#define SC_N  (-2.88539008177f)   // -2*log2(e)

#define OFF_EWHH0 0
#define OFF_EWIH1 6144
#define OFF_EWHH1 12288
#define OFF_DWHH0 18432
#define OFF_DWIH1 24576
#define OFF_DWHH1 30720
#define OFF_EWIH0 36864
#define OFF_FW1   38400

__device__ __forceinline__ ushort_t f2bf(float f) {      // RNE (prep only)
    union { float f; uint_t u; } v; v.f = f;
    uint_t r = v.u + 0x7FFFu + ((v.u >> 16) & 1u);
    return (ushort_t)(r >> 16);
}
__device__ __forceinline__ ushort_t f2bf_h(float f) {    // round-half-up, 2 VALU
    union { float f; uint_t u; } v; v.f = f;
    return (ushort_t)((v.u + 0x8000u) >> 16);
}
__device__ __forceinline__ f32x4 splat4(float v) {
    return (f32x4){v, v, v, v};
}
__device__ __forceinline__ float sig2(float t) {         // sigmoid of pre-scaled acc
    return __builtin_amdgcn_rcpf(1.f + __builtin_amdgcn_exp2f(t));
}
__device__ __forceinline__ void barrier_lds() {
    asm volatile("s_waitcnt lgkmcnt(0)\n\ts_barrier" ::: "memory");
}

// a' = [a.lo | b.lo], b' = [a.hi | b.hi]
__device__ __forceinline__ void pl32swap(float& a, float& b) {
    uintx2 r = __builtin_amdgcn_permlane32_swap(
        __float_as_uint(a), __float_as_uint(b), false, false);
    a = __uint_as_float(r[0]);
    b = __uint_as_float(r[1]);
}
// Pack the 8 valid C-rows (rows 0-7, lanes q=0,1) across all 64 lanes.
__device__ __forceinline__ void spread2(f32x4 v, float& e0, float& e1) {
    float a0 = v[0], a2 = v[2];
    float a1 = v[1], a3 = v[3];
    pl32swap(a0, a2);
    pl32swap(a1, a3);
    e0 = a0; e1 = a1;
}

// ---- DPP 16-lane-group sum: every lane gets the sum of its 16-lane row ----
template <int CTRL>
__device__ __forceinline__ float dpp_add(float acc) {
    int x = __builtin_amdgcn_update_dpp(0, __float_as_int(acc), CTRL, 0xF, 0xF, true);
    return acc + __int_as_float(x);
}
__device__ __forceinline__ float sum16(float v) {
    v = dpp_add<0xB1>(v);    // quad_perm [1,0,3,2]  (xor 1)
    v = dpp_add<0x4E>(v);    // quad_perm [2,3,0,1]  (xor 2)
    v = dpp_add<0x124>(v);   // row_ror:4  (quad-pair)
    v = dpp_add<0x128>(v);   // row_ror:8  (opposite pair)
    return v;
}

// ---------------- prep: fp32 weights -> bf16 MFMA B-fragments ----------------
// Gate matrices PRE-SCALED: rows [0,256) by -log2e, rows [256,384) by -2log2e.
extern "C" __global__ __launch_bounds__(64)
void prep_kernel(const float* __restrict__ eWhh0, const float* __restrict__ eWih1,
                 const float* __restrict__ eWhh1, const float* __restrict__ dWhh0,
                 const float* __restrict__ dWih1, const float* __restrict__ dWhh1,
                 const float* __restrict__ eWih0, const float* __restrict__ fW1,
                 uint4* __restrict__ ws)
{
    const int g = blockIdx.x;
    const int L = threadIdx.x;
    const int n_lo = L & 15, q = L >> 4;

    const float* src; int n, kb, Ksrc, dst16; float sc;
    if (g < 576) {
        const int m = g / 96, lf = g % 96;
        const float* hs[6] = {eWhh0, eWih1, eWhh1, dWhh0, dWih1, dWhh1};
        src = hs[m];
        const int nt = lf >> 2, kf = lf & 3;
        n = nt * 16 + n_lo; kb = kf * 32 + q * 8; Ksrc = 128;
        dst16 = m * 6144 + lf * 64 + L;
        sc = (n < 2 * HD) ? SC_RZ : SC_N;
    } else if (g < 600) {
        const int nt = g - 576;
        src = eWih0; n = nt * 16 + n_lo; kb = q * 8; Ksrc = 16;
        dst16 = OFF_EWIH0 + nt * 64 + L;
        sc = (n < 2 * HD) ? SC_RZ : SC_N;
    } else {
        const int lf = g - 600;
        src = fW1; n = (lf >> 2) * 16 + n_lo; kb = (lf & 3) * 32 + q * 8; Ksrc = 128;
        dst16 = OFF_FW1 + lf * 64 + L;
        sc = 1.f;
    }

    ushort_t h[8];
    #pragma unroll
    for (int j = 0; j < 8; ++j) {
        const int k = kb + j;
        h[j] = (k < Ksrc) ? f2bf(sc * src[n * Ksrc + k]) : (ushort_t)0;
    }
    uint4 o;
    o.x = (uint_t)h[0] | ((uint_t)h[1] << 16);
    o.y = (uint_t)h[2] | ((uint_t)h[3] << 16);
    o.z = (uint_t)h[4] | ((uint_t)h[5] << 16);
    o.w = (uint_t)h[6] | ((uint_t)h[7] << 16);
    ws[dst16] = o;
}

// Spread-combine: 2 valid elements per lane (rows (q&1)*4 + hi2 + e).
__device__ __forceinline__ void combineS(const f32x4& gr, const f32x4& gz,
                                         const f32x4& gn_i, const f32x4& gn_h,
                                         float* hreg, ushort_t* wb)
{
    float r_[2], z_[2], i_[2], n_[2];
    spread2(gr,   r_[0], r_[1]);
    spread2(gz,   z_[0], z_[1]);
    spread2(gn_i, i_[0], i_[1]);
    spread2(gn_h, n_[0], n_[1]);
    #pragma unroll
    for (int e = 0; e < 2; ++e) {
        const float rg = sig2(r_[e]);
        const float zg = sig2(z_[e]);
        const float ng = fmaf(2.f, sig2(i_[e] + rg * n_[e]), -1.f);
        const float hn = fmaf(zg, hreg[e] - ng, ng);
        hreg[e] = hn;
        wb[e * 8] = f2bf_h(hn);
    }
}

extern "C" __global__ __launch_bounds__(NT, 2)
void gru_seq2seq_kernel(
    const float* __restrict__ x,
    const float* __restrict__ ebih0, const float* __restrict__ ebhh0,
    const float* __restrict__ ebih1, const float* __restrict__ ebhh1,
    const float* __restrict__ dWih0, const float* __restrict__ dbih0,
    const float* __restrict__ dbhh0,
    const float* __restrict__ dbih1, const float* __restrict__ dbhh1,
    const float* __restrict__ fb1, const float* __restrict__ fW2,
    const float* __restrict__ fb2,
    const short8* __restrict__ wf,
    float* __restrict__ out)
{
    __shared__ ushort_t h0f[2][4][512];   // [buf][kf][(qq*16+row)*8+jc]; rows 8-15 stay 0
    __shared__ ushort_t h1f[2][4][512];
    __shared__ ushort_t xf[2][512];       // rows 8-15 + k>=16 stay 0
    __shared__ uint4 fw1l[1024];          // fW1 frags (decoder FC)

    const int t = threadIdx.x;
    const int L = t & 63, w = t >> 6;
    const int col16 = L & 15, q = L >> 4;
    const int col = w * 16 + col16;
    const int b0 = blockIdx.x * BT;
    const bool wlo = (w < 4);             // SIMD-mates (w, w+4) get opposite order

    for (int i = t; i < 4096; i += NT) {
        (&h0f[0][0][0])[i] = 0;
        (&h1f[0][0][0])[i] = 0;
    }
    for (int i = t; i < 1024; i += NT) (&xf[0][0])[i] = 0;

    // write offset for the spread layout: rows (q&1)*4 + hi2 + e, e at +8
    const int kfc = col >> 5, qq = (col >> 3) & 3, jc = col & 7;
    const int hi2 = (L >> 5) * 2;
    const int hwoE = kfc * 512 + (qq * 16 + (q & 1) * 4 + hi2) * 8 + jc;

    const int xr = t >> 4, xfeat = t & 15;                 // xr in [0,8) for t<128
    const int xscat = (((xfeat >> 3) * 16) + (xr & 15)) * 8 + (xfeat & 7);
    float xv = (t < 128) ? x[((b0 + xr) * TIN + 0) * NFE + xfeat] : 0.f;

    // encoder per-lane bias scalars, PRE-SCALED
    const float e0_rz = SC_RZ * (ebih0[col] + ebhh0[col]);
    const float e0_zz = SC_RZ * (ebih0[HD + col] + ebhh0[HD + col]);
    const float e0_in = SC_N * ebih0[2 * HD + col];
    const float e0_hn = SC_N * ebhh0[2 * HD + col];
    const float e1_rz = SC_RZ * (ebih1[col] + ebhh1[col]);
    const float e1_zz = SC_RZ * (ebih1[HD + col] + ebhh1[HD + col]);
    const float e1_in = SC_N * ebih1[2 * HD + col];
    const float e1_hn = SC_N * ebhh1[2 * HD + col];

    float h0r[2] = {0, 0};
    float h1r[2] = {0, 0};

    // encoder weights -> registers
    short8 Wa[3][4], Wb[3][4], Wc[3][4];
    short8 We[3];
    #pragma unroll
    for (int t3 = 0; t3 < 3; ++t3) {
        const int nt = w + t3 * 8;
        We[t3] = wf[OFF_EWIH0 + nt * 64 + L];
        #pragma unroll
        for (int kf = 0; kf < 4; ++kf) {
            Wa[t3][kf] = wf[OFF_EWHH0 + (nt * 4 + kf) * 64 + L];
            Wb[t3][kf] = wf[OFF_EWIH1 + (nt * 4 + kf) * 64 + L];
            Wc[t3][kf] = wf[OFF_EWHH1 + (nt * 4 + kf) * 64 + L];
        }
    }

    barrier_lds();
    if (t < 128) {
        (&xf[0][0])[xscat] = f2bf_h(xv);                  // x(0)
        xv = x[((b0 + xr) * TIN + 1) * NFE + xfeat];
    }
    barrier_lds();

    // ---------------- encoder, pipelined: iter i = L0(i) + L1(i-1) ----------
    {
        if (t < 128) {
            (&xf[0][0])[512 + xscat] = f2bf_h(xv);        // x(1) -> xf[1]
            xv = x[((b0 + xr) * TIN + 2) * NFE + xfeat];
        }
        const short8 Ax = *(const short8*)&xf[0][L * 8];
        short8 Ah[4];
        #pragma unroll
        for (int kf = 0; kf < 4; ++kf)
            Ah[kf] = *(const short8*)&h0f[0][kf][L * 8];
        f32x4 gr = splat4(e0_rz), gz = splat4(e0_zz);
        f32x4 gni = splat4(e0_in), gnh = splat4(e0_hn);
        #pragma unroll
        for (int kf = 0; kf < 4; ++kf) {
            gr  = __builtin_amdgcn_mfma_f32_16x16x32_bf16(Ah[kf], Wa[0][kf], gr,  0, 0, 0);
            gz  = __builtin_amdgcn_mfma_f32_16x16x32_bf16(Ah[kf], Wa[1][kf], gz,  0, 0, 0);
            gnh = __builtin_amdgcn_mfma_f32_16x16x32_bf16(Ah[kf], Wa[2][kf], gnh, 0, 0, 0);
        }
        gr  = __builtin_amdgcn_mfma_f32_16x16x32_bf16(Ax, We[0], gr,  0, 0, 0);
        gz  = __builtin_amdgcn_mfma_f32_16x16x32_bf16(Ax, We[1], gz,  0, 0, 0);
        gni = __builtin_amdgcn_mfma_f32_16x16x32_bf16(Ax, We[2], gni, 0, 0, 0);
        combineS(gr, gz, gni, gnh, h0r, &(&h0f[0][0][0])[2048 + hwoE]);
        barrier_lds();
    }

    for (int i = 1; i < TIN; ++i) {
        const int p = i & 1;
        if (t < 128 && i + 1 < TIN) {
            (&xf[0][0])[(1 - p) * 512 + xscat] = f2bf_h(xv);
            if (i + 2 < TIN) xv = x[((b0 + xr) * TIN + i + 2) * NFE + xfeat];
        }
        const short8 Ax = *(const short8*)&xf[p][L * 8];
        short8 Ah0[4], Ah1[4];
        #pragma unroll
        for (int kf = 0; kf < 4; ++kf) {
            Ah0[kf] = *(const short8*)&h0f[p][kf][L * 8];  // h0(i-1)
            Ah1[kf] = *(const short8*)&h1f[p][kf][L * 8];  // h1(i-2)
        }

        if (wlo) {
            // ---- arm LO: [aM][cA][bM][cB] ----------------------------------
            {   // aM + cA
                f32x4 a_r = splat4(e0_rz), a_z = splat4(e0_zz);
                f32x4 a_ni = splat4(e0_in), a_nh = splat4(e0_hn);
                #pragma unroll
                for (int kf = 0; kf < 4; ++kf) {
                    a_r  = __builtin_amdgcn_mfma_f32_16x16x32_bf16(Ah0[kf], Wa[0][kf], a_r,  0, 0, 0);
                    a_z  = __builtin_amdgcn_mfma_f32_16x16x32_bf16(Ah0[kf], Wa[1][kf], a_z,  0, 0, 0);
                    a_nh = __builtin_amdgcn_mfma_f32_16x16x32_bf16(Ah0[kf], Wa[2][kf], a_nh, 0, 0, 0);
                }
                a_r  = __builtin_amdgcn_mfma_f32_16x16x32_bf16(Ax, We[0], a_r,  0, 0, 0);
                a_z  = __builtin_amdgcn_mfma_f32_16x16x32_bf16(Ax, We[1], a_z,  0, 0, 0);
                a_ni = __builtin_amdgcn_mfma_f32_16x16x32_bf16(Ax, We[2], a_ni, 0, 0, 0);
                combineS(a_r, a_z, a_ni, a_nh, h0r, &(&h0f[0][0][0])[(1 - p) * 2048 + hwoE]);
            }
            {   // bM + cB
                f32x4 b_r = splat4(e1_rz), b_z = splat4(e1_zz);
                f32x4 b_ni = splat4(e1_in), b_nh = splat4(e1_hn);
                #pragma unroll
                for (int kf = 0; kf < 4; ++kf) {
                    b_r  = __builtin_amdgcn_mfma_f32_16x16x32_bf16(Ah0[kf], Wb[0][kf], b_r,  0, 0, 0);
                    b_z  = __builtin_amdgcn_mfma_f32_16x16x32_bf16(Ah0[kf], Wb[1][kf], b_z,  0, 0, 0);
                    b_ni = __builtin_amdgcn_mfma_f32_16x16x32_bf16(Ah0[kf], Wb[2][kf], b_ni, 0, 0, 0);
                    b_r  = __builtin_amdgcn_mfma_f32_16x16x32_bf16(Ah1[kf], Wc[0][kf], b_r,  0, 0, 0);
                    b_z  = __builtin_amdgcn_mfma_f32_16x16x32_bf16(Ah1[kf], Wc[1][kf], b_z,  0, 0, 0);
                    b_nh = __builtin_amdgcn_mfma_f32_16x16x32_bf16(Ah1[kf], Wc[2][kf], b_nh, 0, 0, 0);
                }
                combineS(b_r, b_z, b_ni, b_nh, h1r, &(&h1f[0][0][0])[(1 - p) * 2048 + hwoE]);
            }
        } else {
            // ---- arm HI: [bM][cB][aM][cA] ----------------------------------
            {   // bM + cB
                f32x4 b_r = splat4(e1_rz), b_z = splat4(e1_zz);
                f32x4 b_ni = splat4(e1_in), b_nh = splat4(e1_hn);
                #pragma unroll
                for (int kf = 0; kf < 4; ++kf) {
                    b_r  = __builtin_amdgcn_mfma_f32_16x16x32_bf16(Ah0[kf], Wb[0][kf], b_r,  0, 0, 0);
                    b_z  = __builtin_amdgcn_mfma_f32_16x16x32_bf16(Ah0[kf], Wb[1][kf], b_z,  0, 0, 0);
                    b_ni = __builtin_amdgcn_mfma_f32_16x16x32_bf16(Ah0[kf], Wb[2][kf], b_ni, 0, 0, 0);
                    b_r  = __builtin_amdgcn_mfma_f32_16x16x32_bf16(Ah1[kf], Wc[0][kf], b_r,  0, 0, 0);
                    b_z  = __builtin_amdgcn_mfma_f32_16x16x32_bf16(Ah1[kf], Wc[1][kf], b_z,  0, 0, 0);
                    b_nh = __builtin_amdgcn_mfma_f32_16x16x32_bf16(Ah1[kf], Wc[2][kf], b_nh, 0, 0, 0);
                }
                combineS(b_r, b_z, b_ni, b_nh, h1r, &(&h1f[0][0][0])[(1 - p) * 2048 + hwoE]);
            }
            {   // aM + cA
                f32x4 a_r = splat4(e0_rz), a_z = splat4(e0_zz);
                f32x4 a_ni = splat4(e0_in), a_nh = splat4(e0_hn);
                #pragma unroll
                for (int kf = 0; kf < 4; ++kf) {
                    a_r  = __builtin_amdgcn_mfma_f32_16x16x32_bf16(Ah0[kf], Wa[0][kf], a_r,  0, 0, 0);
                    a_z  = __builtin_amdgcn_mfma_f32_16x16x32_bf16(Ah0[kf], Wa[1][kf], a_z,  0, 0, 0);
                    a_nh = __builtin_amdgcn_mfma_f32_16x16x32_bf16(Ah0[kf], Wa[2][kf], a_nh, 0, 0, 0);
                }
                a_r  = __builtin_amdgcn_mfma_f32_16x16x32_bf16(Ax, We[0], a_r,  0, 0, 0);
                a_z  = __builtin_amdgcn_mfma_f32_16x16x32_bf16(Ax, We[1], a_z,  0, 0, 0);
                a_ni = __builtin_amdgcn_mfma_f32_16x16x32_bf16(Ax, We[2], a_ni, 0, 0, 0);
                combineS(a_r, a_z, a_ni, a_nh, h0r, &(&h0f[0][0][0])[(1 - p) * 2048 + hwoE]);
            }
        }
        barrier_lds();
    }

    // epilogue: L1(335).  h0(335) in h0f[0], h1(334) in h1f[0].
    {
        short8 Ai[4], Ah[4];
        #pragma unroll
        for (int kf = 0; kf < 4; ++kf) {
            Ai[kf] = *(const short8*)&h0f[0][kf][L * 8];
            Ah[kf] = *(const short8*)&h1f[0][kf][L * 8];
        }
        f32x4 gr = splat4(e1_rz), gz = splat4(e1_zz);
        f32x4 gni = splat4(e1_in), gnh = splat4(e1_hn);
        #pragma unroll
        for (int kf = 0; kf < 4; ++kf) {
            gr  = __builtin_amdgcn_mfma_f32_16x16x32_bf16(Ai[kf], Wb[0][kf], gr,  0, 0, 0);
            gz  = __builtin_amdgcn_mfma_f32_16x16x32_bf16(Ai[kf], Wb[1][kf], gz,  0, 0, 0);
            gni = __builtin_amdgcn_mfma_f32_16x16x32_bf16(Ai[kf], Wb[2][kf], gni, 0, 0, 0);
            gr  = __builtin_amdgcn_mfma_f32_16x16x32_bf16(Ah[kf], Wc[0][kf], gr,  0, 0, 0);
            gz  = __builtin_amdgcn_mfma_f32_16x16x32_bf16(Ah[kf], Wc[1][kf], gz,  0, 0, 0);
            gnh = __builtin_amdgcn_mfma_f32_16x16x32_bf16(Ah[kf], Wc[2][kf], gnh, 0, 0, 0);
        }
        combineS(gr, gz, gni, gnh, h1r, &(&h1f[0][0][0])[2048 + hwoE]);  // h1(-1) -> h1f[1]
        barrier_lds();
    }

    asm volatile("" ::: "memory");

    // ---- decoder prologue: weights, fW1->LDS, biases, ghA(0), h0(0) --------
    #pragma unroll
    for (int t3 = 0; t3 < 3; ++t3) {
        const int nt = w + t3 * 8;
        #pragma unroll
        for (int kf = 0; kf < 4; ++kf) {
            Wa[t3][kf] = wf[OFF_DWHH0 + (nt * 4 + kf) * 64 + L];
            Wb[t3][kf] = wf[OFF_DWIH1 + (nt * 4 + kf) * 64 + L];
            Wc[t3][kf] = wf[OFF_DWHH1 + (nt * 4 + kf) * 64 + L];
        }
    }
    for (int i = t; i < 1024; i += NT) fw1l[i] = ((const uint4*)wf)[OFF_FW1 + i];

    const float d0_rz = SC_RZ * (dbih0[col] + dbhh0[col]);
    const float d0_zz = SC_RZ * (dbih0[HD + col] + dbhh0[HD + col]);
    const float d0_in = SC_N * dbih0[2 * HD + col];
    const float d0_hn = SC_N * dbhh0[2 * HD + col];
    const float d1_rz = SC_RZ * (dbih1[col] + dbhh1[col]);
    const float d1_zz = SC_RZ * (dbih1[HD + col] + dbhh1[HD + col]);
    const float d1_in = SC_N * dbih1[2 * HD + col];
    const float d1_hn = SC_N * dbhh1[2 * HD + col];
    const float w0r = SC_RZ * dWih0[col];
    const float w0z = SC_RZ * dWih0[HD + col];
    const float w0n = SC_N * dWih0[2 * HD + col];
    float f1bv[4], w2v[4];
    #pragma unroll
    for (int nt = 0; nt < 4; ++nt) {
        f1bv[nt] = fb1[nt * 16 + col16];
        w2v[nt]  = fW2[nt * 16 + col16];
    }
    const float fb2v = fb2[0];
    float ivr[2] = {0.f, 0.f};

    // prologue: ghA from h0_enc, then combine h0(0) (inp(-1)=0) -> h0f[0]
    {
        short8 Ah[4];
        #pragma unroll
        for (int kf = 0; kf < 4; ++kf)
            Ah[kf] = *(const short8*)&h0f[0][kf][L * 8];
        f32x4 g0 = splat4(d0_rz), g1 = splat4(d0_zz), g2 = splat4(d0_hn);
        #pragma unroll
        for (int kf = 0; kf < 4; ++kf) {
            g0 = __builtin_amdgcn_mfma_f32_16x16x32_bf16(Ah[kf], Wa[0][kf], g0, 0, 0, 0);
            g1 = __builtin_amdgcn_mfma_f32_16x16x32_bf16(Ah[kf], Wa[1][kf], g1, 0, 0, 0);
            g2 = __builtin_amdgcn_mfma_f32_16x16x32_bf16(Ah[kf], Wa[2][kf], g2, 0, 0, 0);
        }
        float g0e[2], g1e[2], g2e[2];
        spread2(g0, g0e[0], g0e[1]);
        spread2(g1, g1e[0], g1e[1]);
        spread2(g2, g2e[0], g2e[1]);
        barrier_lds();   // everyone done reading h0f[0] before overwrite
        ushort_t* wb = &(&h0f[0][0][0])[0 + hwoE];
        #pragma unroll
        for (int e = 0; e < 2; ++e) {
            const float rg = sig2(g0e[e]);
            const float zg = sig2(g1e[e]);
            const float ng = fmaf(2.f, sig2(d0_in + rg * g2e[e]), -1.f);
            const float hn = fmaf(zg, h0r[e] - ng, ng);
            h0r[e] = hn;
            wb[e * 8] = f2bf_h(hn);
        }
    }
    barrier_lds();

    // ---------------- decoder: 2 balanced phases/step ----------------------
    // h0(s) in h0f[s&1]; h1(s) in h1f[s&1] (h1(-1) in h1f[1]).
    for (int s = 0; s < TOUT; ++s) {
        const int p = s & 1;

        // ----- P2(s): L1(s) only (24 MFMA) ---------------------------------
        {
            short8 Ai[4], Ah[4];
            #pragma unroll
            for (int kf = 0; kf < 4; ++kf) {
                Ai[kf] = *(const short8*)&h0f[p][kf][L * 8];      // h0(s)
                Ah[kf] = *(const short8*)&h1f[1 - p][kf][L * 8];  // h1(s-1)
            }
            f32x4 gr = splat4(d1_rz), gz = splat4(d1_zz);
            f32x4 gni = splat4(d1_in), gnh = splat4(d1_hn);
            #pragma unroll
            for (int kf = 0; kf < 4; ++kf) {
                gr  = __builtin_amdgcn_mfma_f32_16x16x32_bf16(Ai[kf], Wb[0][kf], gr,  0, 0, 0);
                gz  = __builtin_amdgcn_mfma_f32_16x16x32_bf16(Ai[kf], Wb[1][kf], gz,  0, 0, 0);
                gni = __builtin_amdgcn_mfma_f32_16x16x32_bf16(Ai[kf], Wb[2][kf], gni, 0, 0, 0);
                gr  = __builtin_amdgcn_mfma_f32_16x16x32_bf16(Ah[kf], Wc[0][kf], gr,  0, 0, 0);
                gz  = __builtin_amdgcn_mfma_f32_16x16x32_bf16(Ah[kf], Wc[1][kf], gz,  0, 0, 0);
                gnh = __builtin_amdgcn_mfma_f32_16x16x32_bf16(Ah[kf], Wc[2][kf], gnh, 0, 0, 0);
            }
            combineS(gr, gz, gni, gnh, h1r, &(&h1f[0][0][0])[p * 2048 + hwoE]);  // h1(s)
        }
        barrier_lds();

        // ----- P1: FC(s) + ghA(s+1) + combine h0(s+1) (16+12 MFMA) ---------
        {
            short8 Af[4], Ah[4];
            #pragma unroll
            for (int kf = 0; kf < 4; ++kf) {
                Af[kf] = *(const short8*)&h1f[p][kf][L * 8];      // h1(s)
                Ah[kf] = *(const short8*)&h0f[p][kf][L * 8];      // h0(s)
            }
            // ghA(s+1) = dWhh0 . h0(s), bias-init (consumed below, in-phase)
            f32x4 g0 = splat4(d0_rz), g1 = splat4(d0_zz), g2 = splat4(d0_hn);
            f32x4 fc[4];
            #pragma unroll
            for (int nt = 0; nt < 4; ++nt) fc[nt] = splat4(0.f);
            #pragma unroll
            for (int kf = 0; kf < 4; ++kf) {
                g0 = __builtin_amdgcn_mfma_f32_16x16x32_bf16(Ah[kf], Wa[0][kf], g0, 0, 0, 0);
                g1 = __builtin_amdgcn_mfma_f32_16x16x32_bf16(Ah[kf], Wa[1][kf], g1, 0, 0, 0);
                g2 = __builtin_amdgcn_mfma_f32_16x16x32_bf16(Ah[kf], Wa[2][kf], g2, 0, 0, 0);
                #pragma unroll
                for (int nt = 0; nt < 4; ++nt) {
                    const short8 b = *(const short8*)&fw1l[(nt * 4 + kf) * 64 + L];
                    fc[nt] = __builtin_amdgcn_mfma_f32_16x16x32_bf16(Af[kf], b, fc[nt], 0, 0, 0);
                }
            }
            float g0e[2], g1e[2], g2e[2], fe0[4], fe1[4];
            #pragma unroll
            for (int nt = 0; nt < 4; ++nt) spread2(fc[nt], fe0[nt], fe1[nt]);
            float ps[2];
            #pragma unroll
            for (int e = 0; e < 2; ++e) {
                float s_ = 0.f;
                #pragma unroll
                for (int nt = 0; nt < 4; ++nt) {
                    const float v = (e == 0) ? fe0[nt] : fe1[nt];
                    s_ = fmaf(fmaxf(v + f1bv[nt], 0.f), w2v[nt], s_);
                }
                ps[e] = s_;
            }
            #pragma unroll
            for (int e = 0; e < 2; ++e) {
                ps[e] = sum16(ps[e]);                      // DPP 16-lane-group sum
                ivr[e] = fmaxf(ps[e] + fb2v, 0.f);
            }
            spread2(g0, g0e[0], g0e[1]);
            spread2(g1, g1e[0], g1e[1]);
            spread2(g2, g2e[0], g2e[1]);
            if (w == 0 && col16 == 0) {                    // lanes 0,16,32,48
                #pragma unroll
                for (int e = 0; e < 2; ++e)
                    out[(b0 + (q & 1) * 4 + hi2 + e) * TOUT + s] = ivr[e];
            }
            // combine h0(s+1) -> h0f[1-p]
            ushort_t* wb = &(&h0f[0][0][0])[(1 - p) * 2048 + hwoE];
            #pragma unroll
            for (int e = 0; e < 2; ++e) {
                const float iv = ivr[e];
                const float rg = sig2(fmaf(iv, w0r, g0e[e]));
                const float zg = sig2(fmaf(iv, w0z, g1e[e]));
                const float tt = fmaf(iv, w0n, d0_in) + rg * g2e[e];
                const float ng = fmaf(2.f, sig2(tt), -1.f);
                const float hn = fmaf(zg, h0r[e] - ng, ng);
                h0r[e] = hn;
                wb[e * 8] = f2bf_h(hn);
            }
        }
        barrier_lds();
    }
}

extern "C" void kernel_launch(void* const* d_in, const int* in_sizes, int n_in,
                              void* d_out, int out_size, void* d_ws, size_t ws_size,
                              hipStream_t stream) {
    const float* x     = (const float*)d_in[0];
    const float* eWih0 = (const float*)d_in[1];
    const float* eWhh0 = (const float*)d_in[2];
    const float* ebih0 = (const float*)d_in[3];
    const float* ebhh0 = (const float*)d_in[4];
    const float* eWih1 = (const float*)d_in[5];
    const float* eWhh1 = (const float*)d_in[6];
    const float* ebih1 = (const float*)d_in[7];
    const float* ebhh1 = (const float*)d_in[8];
    const float* dWih0 = (const float*)d_in[9];
    const float* dWhh0 = (const float*)d_in[10];
    const float* dbih0 = (const float*)d_in[11];
    const float* dbhh0 = (const float*)d_in[12];
    const float* dWih1 = (const float*)d_in[13];
    const float* dWhh1 = (const float*)d_in[14];
    const float* dbih1 = (const float*)d_in[15];
    const float* dbhh1 = (const float*)d_in[16];
    const float* fW1   = (const float*)d_in[17];
    const float* fb1   = (const float*)d_in[18];
    const float* fW2   = (const float*)d_in[19];
    const float* fb2   = (const float*)d_in[20];
    float* out = (float*)d_out;

    hipLaunchKernelGGL(prep_kernel, dim3(616), dim3(64), 0, stream,
                       eWhh0, eWih1, eWhh1, dWhh0, dWih1, dWhh1, eWih0, fW1,
                       (uint4*)d_ws);
    hipLaunchKernelGGL(gru_seq2seq_kernel, dim3(NB), dim3(NT), 0, stream,
                       x, ebih0, ebhh0, ebih1, ebhh1,
                       dWih0, dbih0, dbhh0, dbih1, dbhh1,
                       fb1, fW2, fb2,
                       (const short8*)d_ws, out);
}

// Round 6
// 737.470 us; speedup vs baseline: 1.1361x; 1.0714x over previous
//
#include <hip/hip_runtime.h>

// GRU seq2seq, MI355X gfx950. Round 16: VALU-diet on the R11 structure.
//   R12/R14/R15 all proved: any reordering to overlap MFMA/combine spills
//   (WRITE_SIZE 1.3MB -> 6.5-22MB) and regresses. So: keep R11's program
//   order exactly, shrink the VALU stream with pressure-REDUCING changes:
//   (1) zero-C MFMA init: acc = mfma(A,B, zf) with a persistent zero f32x4
//       (D!=C is native) -> kills 32 bias-init movs/phase (28/step decoder).
//   (2) biases become post-spread scalar adds inside combine (16 adds).
//   (3) unroll-by-2 encoder+decoder loops: ping-pong index p literal ->
//       all LDS offsets fold to base+imm, no per-phase address VALU.
//   (4) DPP sum16 FC-reduce (validated R14/R15).
//   Structure: 256 blocks x BT=8, spread-2 combine (permlane32_swap),
//   register/AGPR-resident weights, 1-barrier encoder, 2-phase decoder.

typedef unsigned short ushort_t;
typedef unsigned int uint_t;
typedef __attribute__((ext_vector_type(8))) short short8;
typedef __attribute__((ext_vector_type(4))) float f32x4;
typedef __attribute__((ext_vector_type(2))) unsigned int uintx2;

#define BT   8
#define NT   512
#define HD   128
#define TIN  336
#define TOUT 168
#define NFE  16
#define NB   256

#define SC_RZ (-1.44269504089f)   // -log2(e)
#define SC_N  (-2.88539008177f)   // -2*log2(e)

#define OFF_EWHH0 0
#define OFF_EWIH1 6144
#define OFF_EWHH1 12288
#define OFF_DWHH0 18432
#define OFF_DWIH1 24576
#define OFF_DWHH1 30720
#define OFF_EWIH0 36864
#define OFF_FW1   38400

#define MF(a_, b_, c_) __builtin_amdgcn_mfma_f32_16x16x32_bf16((a_), (b_), (c_), 0, 0, 0)

__device__ __forceinline__ ushort_t f2bf(float f) {      // RNE (prep only)
    union { float f; uint_t u; } v; v.f = f;
    uint_t r = v.u + 0x7FFFu + ((v.u >> 16) & 1u);
    return (ushort_t)(r >> 16);
}
__device__ __forceinline__ ushort_t f2bf_h(float f) {    // round-half-up, 2 VALU
    union { float f; uint_t u; } v; v.f = f;
    return (ushort_t)((v.u + 0x8000u) >> 16);
}
__device__ __forceinline__ float sig2(float t) {         // sigmoid of pre-scaled acc
    return __builtin_amdgcn_rcpf(1.f + __builtin_amdgcn_exp2f(t));
}
__device__ __forceinline__ void barrier_lds() {
    asm volatile("s_waitcnt lgkmcnt(0)\n\ts_barrier" ::: "memory");
}

// a' = [a.lo | b.lo], b' = [a.hi | b.hi]
__device__ __forceinline__ void pl32swap(float& a, float& b) {
    uintx2 r = __builtin_amdgcn_permlane32_swap(
        __float_as_uint(a), __float_as_uint(b), false, false);
    a = __uint_as_float(r[0]);
    b = __uint_as_float(r[1]);
}
// Pack the 8 valid C-rows (rows 0-7, lanes q=0,1) across all 64 lanes.
__device__ __forceinline__ void spread2(f32x4 v, float& e0, float& e1) {
    float a0 = v[0], a2 = v[2];
    float a1 = v[1], a3 = v[3];
    pl32swap(a0, a2);
    pl32swap(a1, a3);
    e0 = a0; e1 = a1;
}

// ---- DPP 16-lane-group sum: every lane gets the sum of its 16-lane row ----
template <int CTRL>
__device__ __forceinline__ float dpp_add(float acc) {
    int x = __builtin_amdgcn_update_dpp(0, __float_as_int(acc), CTRL, 0xF, 0xF, true);
    return acc + __int_as_float(x);
}
__device__ __forceinline__ float sum16(float v) {
    v = dpp_add<0xB1>(v);    // quad_perm [1,0,3,2]  (xor 1)
    v = dpp_add<0x4E>(v);    // quad_perm [2,3,0,1]  (xor 2)
    v = dpp_add<0x124>(v);   // row_ror:4  (quad-pair)
    v = dpp_add<0x128>(v);   // row_ror:8  (opposite pair)
    return v;
}

// ---------------- prep: fp32 weights -> bf16 MFMA B-fragments ----------------
// Gate matrices PRE-SCALED: rows [0,256) by -log2e, rows [256,384) by -2log2e.
extern "C" __global__ __launch_bounds__(64)
void prep_kernel(const float* __restrict__ eWhh0, const float* __restrict__ eWih1,
                 const float* __restrict__ eWhh1, const float* __restrict__ dWhh0,
                 const float* __restrict__ dWih1, const float* __restrict__ dWhh1,
                 const float* __restrict__ eWih0, const float* __restrict__ fW1,
                 uint4* __restrict__ ws)
{
    const int g = blockIdx.x;
    const int L = threadIdx.x;
    const int n_lo = L & 15, q = L >> 4;

    const float* src; int n, kb, Ksrc, dst16; float sc;
    if (g < 576) {
        const int m = g / 96, lf = g % 96;
        const float* hs[6] = {eWhh0, eWih1, eWhh1, dWhh0, dWih1, dWhh1};
        src = hs[m];
        const int nt = lf >> 2, kf = lf & 3;
        n = nt * 16 + n_lo; kb = kf * 32 + q * 8; Ksrc = 128;
        dst16 = m * 6144 + lf * 64 + L;
        sc = (n < 2 * HD) ? SC_RZ : SC_N;
    } else if (g < 600) {
        const int nt = g - 576;
        src = eWih0; n = nt * 16 + n_lo; kb = q * 8; Ksrc = 16;
        dst16 = OFF_EWIH0 + nt * 64 + L;
        sc = (n < 2 * HD) ? SC_RZ : SC_N;
    } else {
        const int lf = g - 600;
        src = fW1; n = (lf >> 2) * 16 + n_lo; kb = (lf & 3) * 32 + q * 8; Ksrc = 128;
        dst16 = OFF_FW1 + lf * 64 + L;
        sc = 1.f;
    }

    ushort_t h[8];
    #pragma unroll
    for (int j = 0; j < 8; ++j) {
        const int k = kb + j;
        h[j] = (k < Ksrc) ? f2bf(sc * src[n * Ksrc + k]) : (ushort_t)0;
    }
    uint4 o;
    o.x = (uint_t)h[0] | ((uint_t)h[1] << 16);
    o.y = (uint_t)h[2] | ((uint_t)h[3] << 16);
    o.z = (uint_t)h[4] | ((uint_t)h[5] << 16);
    o.w = (uint_t)h[6] | ((uint_t)h[7] << 16);
    ws[dst16] = o;
}

// Spread-combine with POST-spread biases (accs are zero-C initialized).
__device__ __forceinline__ void combineS(const f32x4& gr, const f32x4& gz,
                                         const f32x4& gn_i, const f32x4& gn_h,
                                         float brz, float bzz, float bin, float bhn,
                                         float* hreg, ushort_t* wb)
{
    float r_[2], z_[2], i_[2], n_[2];
    spread2(gr,   r_[0], r_[1]);
    spread2(gz,   z_[0], z_[1]);
    spread2(gn_i, i_[0], i_[1]);
    spread2(gn_h, n_[0], n_[1]);
    #pragma unroll
    for (int e = 0; e < 2; ++e) {
        const float rg = sig2(r_[e] + brz);
        const float zg = sig2(z_[e] + bzz);
        const float ng = fmaf(2.f, sig2((i_[e] + bin) + rg * (n_[e] + bhn)), -1.f);
        const float hn = fmaf(zg, hreg[e] - ng, ng);
        hreg[e] = hn;
        wb[e * 8] = f2bf_h(hn);
    }
}

// ---------------- encoder steady-state body (P_ is a literal) ---------------
#define ENC_BODY(i_, P_) do {                                                  \
    if (t < 128 && (i_) + 1 < TIN) {                                           \
        (&xf[0][0])[(1 - (P_)) * 512 + xscat] = f2bf_h(xv);                    \
        if ((i_) + 2 < TIN) xv = x[((b0 + xr) * TIN + (i_) + 2) * NFE + xfeat];\
    }                                                                          \
    const short8 Ax = *(const short8*)&xf[P_][L * 8];                          \
    short8 Ah0[4], Ah1[4];                                                     \
    _Pragma("unroll")                                                          \
    for (int kf = 0; kf < 4; ++kf) {                                           \
        Ah0[kf] = *(const short8*)&h0f[P_][kf][L * 8];                         \
        Ah1[kf] = *(const short8*)&h1f[P_][kf][L * 8];                         \
    }                                                                          \
    f32x4 a_r  = MF(Ah0[0], Wa[0][0], zf);                                     \
    f32x4 a_z  = MF(Ah0[0], Wa[1][0], zf);                                     \
    f32x4 a_nh = MF(Ah0[0], Wa[2][0], zf);                                     \
    f32x4 b_r  = MF(Ah0[0], Wb[0][0], zf);                                     \
    f32x4 b_z  = MF(Ah0[0], Wb[1][0], zf);                                     \
    f32x4 b_ni = MF(Ah0[0], Wb[2][0], zf);                                     \
    f32x4 b_nh = MF(Ah1[0], Wc[2][0], zf);                                     \
    b_r  = MF(Ah1[0], Wc[0][0], b_r);                                          \
    b_z  = MF(Ah1[0], Wc[1][0], b_z);                                          \
    _Pragma("unroll")                                                          \
    for (int kf = 1; kf < 4; ++kf) {                                           \
        a_r  = MF(Ah0[kf], Wa[0][kf], a_r);                                    \
        a_z  = MF(Ah0[kf], Wa[1][kf], a_z);                                    \
        a_nh = MF(Ah0[kf], Wa[2][kf], a_nh);                                   \
        b_r  = MF(Ah0[kf], Wb[0][kf], b_r);                                    \
        b_z  = MF(Ah0[kf], Wb[1][kf], b_z);                                    \
        b_ni = MF(Ah0[kf], Wb[2][kf], b_ni);                                   \
        b_r  = MF(Ah1[kf], Wc[0][kf], b_r);                                    \
        b_z  = MF(Ah1[kf], Wc[1][kf], b_z);                                    \
        b_nh = MF(Ah1[kf], Wc[2][kf], b_nh);                                   \
    }                                                                          \
    a_r = MF(Ax, We[0], a_r);                                                  \
    a_z = MF(Ax, We[1], a_z);                                                  \
    f32x4 a_ni = MF(Ax, We[2], zf);                                            \
    combineS(a_r, a_z, a_ni, a_nh, e0_rz, e0_zz, e0_in, e0_hn, h0r,            \
             &(&h0f[0][0][0])[(1 - (P_)) * 2048 + hwoE]);                      \
    combineS(b_r, b_z, b_ni, b_nh, e1_rz, e1_zz, e1_in, e1_hn, h1r,            \
             &(&h1f[0][0][0])[(1 - (P_)) * 2048 + hwoE]);                      \
    barrier_lds();                                                             \
} while (0)

// ---------------- decoder step body (P_, Q_=1-P_ are literals) --------------
#define DEC_BODY(s_, P_, Q_) do {                                              \
    { /* P2(s): L1(s) */                                                       \
        short8 Ai[4], Ah[4];                                                   \
        _Pragma("unroll")                                                      \
        for (int kf = 0; kf < 4; ++kf) {                                       \
            Ai[kf] = *(const short8*)&h0f[P_][kf][L * 8];                      \
            Ah[kf] = *(const short8*)&h1f[Q_][kf][L * 8];                      \
        }                                                                      \
        f32x4 gr  = MF(Ai[0], Wb[0][0], zf);                                   \
        f32x4 gz  = MF(Ai[0], Wb[1][0], zf);                                   \
        f32x4 gni = MF(Ai[0], Wb[2][0], zf);                                   \
        f32x4 gnh = MF(Ah[0], Wc[2][0], zf);                                   \
        gr = MF(Ah[0], Wc[0][0], gr);                                          \
        gz = MF(Ah[0], Wc[1][0], gz);                                          \
        _Pragma("unroll")                                                      \
        for (int kf = 1; kf < 4; ++kf) {                                       \
            gr  = MF(Ai[kf], Wb[0][kf], gr);                                   \
            gz  = MF(Ai[kf], Wb[1][kf], gz);                                   \
            gni = MF(Ai[kf], Wb[2][kf], gni);                                  \
            gr  = MF(Ah[kf], Wc[0][kf], gr);                                   \
            gz  = MF(Ah[kf], Wc[1][kf], gz);                                   \
            gnh = MF(Ah[kf], Wc[2][kf], gnh);                                  \
        }                                                                      \
        combineS(gr, gz, gni, gnh, d1_rz, d1_zz, d1_in, d1_hn, h1r,            \
                 &(&h1f[0][0][0])[(P_) * 2048 + hwoE]);                        \
    }                                                                          \
    barrier_lds();                                                             \
    { /* P1: FC(s) + ghA(s+1) + combine h0(s+1) */                             \
        short8 Af[4], Ah[4];                                                   \
        _Pragma("unroll")                                                      \
        for (int kf = 0; kf < 4; ++kf) {                                       \
            Af[kf] = *(const short8*)&h1f[P_][kf][L * 8];                      \
            Ah[kf] = *(const short8*)&h0f[P_][kf][L * 8];                      \
        }                                                                      \
        f32x4 g0 = MF(Ah[0], Wa[0][0], zf);                                    \
        f32x4 g1 = MF(Ah[0], Wa[1][0], zf);                                    \
        f32x4 g2 = MF(Ah[0], Wa[2][0], zf);                                    \
        f32x4 fc[4];                                                           \
        _Pragma("unroll")                                                      \
        for (int nt = 0; nt < 4; ++nt)                                         \
            fc[nt] = MF(Af[0], *(const short8*)&fw1l[(nt * 4) * 64 + L], zf);  \
        _Pragma("unroll")                                                      \
        for (int kf = 1; kf < 4; ++kf) {                                       \
            g0 = MF(Ah[kf], Wa[0][kf], g0);                                    \
            g1 = MF(Ah[kf], Wa[1][kf], g1);                                    \
            g2 = MF(Ah[kf], Wa[2][kf], g2);                                    \
            _Pragma("unroll")                                                  \
            for (int nt = 0; nt < 4; ++nt) {                                   \
                const short8 bfr = *(const short8*)&fw1l[(nt * 4 + kf) * 64 + L]; \
                fc[nt] = MF(Af[kf], bfr, fc[nt]);                              \
            }                                                                  \
        }                                                                      \
        float g0e[2], g1e[2], g2e[2], fe0[4], fe1[4];                          \
        _Pragma("unroll")                                                      \
        for (int nt = 0; nt < 4; ++nt) spread2(fc[nt], fe0[nt], fe1[nt]);      \
        float ps[2];                                                           \
        _Pragma("unroll")                                                      \
        for (int e = 0; e < 2; ++e) {                                          \
            float s2_ = 0.f;                                                   \
            _Pragma("unroll")                                                  \
            for (int nt = 0; nt < 4; ++nt) {                                   \
                const float v = (e == 0) ? fe0[nt] : fe1[nt];                  \
                s2_ = fmaf(fmaxf(v + f1bv[nt], 0.f), w2v[nt], s2_);            \
            }                                                                  \
            ps[e] = s2_;                                                       \
        }                                                                      \
        _Pragma("unroll")                                                      \
        for (int e = 0; e < 2; ++e) {                                          \
            ps[e] = sum16(ps[e]);                                              \
            ivr[e] = fmaxf(ps[e] + fb2v, 0.f);                                 \
        }                                                                      \
        spread2(g0, g0e[0], g0e[1]);                                           \
        spread2(g1, g1e[0], g1e[1]);                                           \
        spread2(g2, g2e[0], g2e[1]);                                           \
        if (w == 0 && col16 == 0) {                                            \
            _Pragma("unroll")                                                  \
            for (int e = 0; e < 2; ++e)                                        \
                out[(b0 + (q & 1) * 4 + hi2 + e) * TOUT + (s_)] = ivr[e];      \
        }                                                                      \
        ushort_t* wbp = &(&h0f[0][0][0])[(Q_) * 2048 + hwoE];                  \
        _Pragma("unroll")                                                      \
        for (int e = 0; e < 2; ++e) {                                          \
            const float iv = ivr[e];                                           \
            const float rg = sig2(fmaf(iv, w0r, g0e[e] + d0_rz));              \
            const float zg = sig2(fmaf(iv, w0z, g1e[e] + d0_zz));              \
            const float tt = fmaf(iv, w0n, d0_in) + rg * (g2e[e] + d0_hn);     \
            const float ng = fmaf(2.f, sig2(tt), -1.f);                        \
            const float hn = fmaf(zg, h0r[e] - ng, ng);                        \
            h0r[e] = hn;                                                       \
            wbp[e * 8] = f2bf_h(hn);                                           \
        }                                                                      \
    }                                                                          \
    barrier_lds();                                                             \
} while (0)

extern "C" __global__ __launch_bounds__(NT, 2)
void gru_seq2seq_kernel(
    const float* __restrict__ x,
    const float* __restrict__ ebih0, const float* __restrict__ ebhh0,
    const float* __restrict__ ebih1, const float* __restrict__ ebhh1,
    const float* __restrict__ dWih0, const float* __restrict__ dbih0,
    const float* __restrict__ dbhh0,
    const float* __restrict__ dbih1, const float* __restrict__ dbhh1,
    const float* __restrict__ fb1, const float* __restrict__ fW2,
    const float* __restrict__ fb2,
    const short8* __restrict__ wf,
    float* __restrict__ out)
{
    __shared__ ushort_t h0f[2][4][512];   // [buf][kf][(qq*16+row)*8+jc]; rows 8-15 stay 0
    __shared__ ushort_t h1f[2][4][512];
    __shared__ ushort_t xf[2][512];       // rows 8-15 + k>=16 stay 0
    __shared__ uint4 fw1l[1024];          // fW1 frags (decoder FC)

    const int t = threadIdx.x;
    const int L = t & 63, w = t >> 6;
    const int col16 = L & 15, q = L >> 4;
    const int col = w * 16 + col16;
    const int b0 = blockIdx.x * BT;

    for (int i = t; i < 4096; i += NT) {
        (&h0f[0][0][0])[i] = 0;
        (&h1f[0][0][0])[i] = 0;
    }
    for (int i = t; i < 1024; i += NT) (&xf[0][0])[i] = 0;

    // write offset for the spread layout: rows (q&1)*4 + hi2 + e, e at +8
    const int kfc = col >> 5, qq = (col >> 3) & 3, jc = col & 7;
    const int hi2 = (L >> 5) * 2;
    const int hwoE = kfc * 512 + (qq * 16 + (q & 1) * 4 + hi2) * 8 + jc;

    const int xr = t >> 4, xfeat = t & 15;                 // xr in [0,8) for t<128
    const int xscat = (((xfeat >> 3) * 16) + (xr & 15)) * 8 + (xfeat & 7);
    float xv = (t < 128) ? x[((b0 + xr) * TIN + 0) * NFE + xfeat] : 0.f;

    // encoder per-lane bias scalars, PRE-SCALED
    const float e0_rz = SC_RZ * (ebih0[col] + ebhh0[col]);
    const float e0_zz = SC_RZ * (ebih0[HD + col] + ebhh0[HD + col]);
    const float e0_in = SC_N * ebih0[2 * HD + col];
    const float e0_hn = SC_N * ebhh0[2 * HD + col];
    const float e1_rz = SC_RZ * (ebih1[col] + ebhh1[col]);
    const float e1_zz = SC_RZ * (ebih1[HD + col] + ebhh1[HD + col]);
    const float e1_in = SC_N * ebih1[2 * HD + col];
    const float e1_hn = SC_N * ebhh1[2 * HD + col];

    float h0r[2] = {0, 0};
    float h1r[2] = {0, 0};

    const f32x4 zf = {0.f, 0.f, 0.f, 0.f};   // persistent zero C-operand

    // encoder weights -> registers
    short8 Wa[3][4], Wb[3][4], Wc[3][4];
    short8 We[3];
    #pragma unroll
    for (int t3 = 0; t3 < 3; ++t3) {
        const int nt = w + t3 * 8;
        We[t3] = wf[OFF_EWIH0 + nt * 64 + L];
        #pragma unroll
        for (int kf = 0; kf < 4; ++kf) {
            Wa[t3][kf] = wf[OFF_EWHH0 + (nt * 4 + kf) * 64 + L];
            Wb[t3][kf] = wf[OFF_EWIH1 + (nt * 4 + kf) * 64 + L];
            Wc[t3][kf] = wf[OFF_EWHH1 + (nt * 4 + kf) * 64 + L];
        }
    }

    barrier_lds();
    if (t < 128) {
        (&xf[0][0])[xscat] = f2bf_h(xv);                  // x(0)
        xv = x[((b0 + xr) * TIN + 1) * NFE + xfeat];
    }
    barrier_lds();

    // ---------------- encoder, pipelined: iter i = L0(i) + L1(i-1) ----------
    {   // i = 0: L0 only
        if (t < 128) {
            (&xf[0][0])[512 + xscat] = f2bf_h(xv);        // x(1) -> xf[1]
            xv = x[((b0 + xr) * TIN + 2) * NFE + xfeat];
        }
        const short8 Ax = *(const short8*)&xf[0][L * 8];
        short8 Ah[4];
        #pragma unroll
        for (int kf = 0; kf < 4; ++kf)
            Ah[kf] = *(const short8*)&h0f[0][kf][L * 8];
        f32x4 gr  = MF(Ah[0], Wa[0][0], zf);
        f32x4 gz  = MF(Ah[0], Wa[1][0], zf);
        f32x4 gnh = MF(Ah[0], Wa[2][0], zf);
        #pragma unroll
        for (int kf = 1; kf < 4; ++kf) {
            gr  = MF(Ah[kf], Wa[0][kf], gr);
            gz  = MF(Ah[kf], Wa[1][kf], gz);
            gnh = MF(Ah[kf], Wa[2][kf], gnh);
        }
        gr = MF(Ax, We[0], gr);
        gz = MF(Ax, We[1], gz);
        f32x4 gni = MF(Ax, We[2], zf);
        combineS(gr, gz, gni, gnh, e0_rz, e0_zz, e0_in, e0_hn, h0r,
                 &(&h0f[0][0][0])[2048 + hwoE]);
        barrier_lds();
    }

    for (int i = 1; i + 1 < TIN; i += 2) {
        ENC_BODY(i, 1);
        ENC_BODY(i + 1, 0);
    }
    ENC_BODY(TIN - 1, 1);   // i = 335

    // epilogue: L1(335).  h0(335) in h0f[0], h1(334) in h1f[0].
    {
        short8 Ai[4], Ah[4];
        #pragma unroll
        for (int kf = 0; kf < 4; ++kf) {
            Ai[kf] = *(const short8*)&h0f[0][kf][L * 8];
            Ah[kf] = *(const short8*)&h1f[0][kf][L * 8];
        }
        f32x4 gr  = MF(Ai[0], Wb[0][0], zf);
        f32x4 gz  = MF(Ai[0], Wb[1][0], zf);
        f32x4 gni = MF(Ai[0], Wb[2][0], zf);
        f32x4 gnh = MF(Ah[0], Wc[2][0], zf);
        gr = MF(Ah[0], Wc[0][0], gr);
        gz = MF(Ah[0], Wc[1][0], gz);
        #pragma unroll
        for (int kf = 1; kf < 4; ++kf) {
            gr  = MF(Ai[kf], Wb[0][kf], gr);
            gz  = MF(Ai[kf], Wb[1][kf], gz);
            gni = MF(Ai[kf], Wb[2][kf], gni);
            gr  = MF(Ah[kf], Wc[0][kf], gr);
            gz  = MF(Ah[kf], Wc[1][kf], gz);
            gnh = MF(Ah[kf], Wc[2][kf], gnh);
        }
        combineS(gr, gz, gni, gnh, e1_rz, e1_zz, e1_in, e1_hn, h1r,
                 &(&h1f[0][0][0])[2048 + hwoE]);  // h1(-1) -> h1f[1]
        barrier_lds();
    }

    asm volatile("" ::: "memory");

    // ---- decoder prologue: weights, fW1->LDS, biases, ghA(0), h0(0) --------
    #pragma unroll
    for (int t3 = 0; t3 < 3; ++t3) {
        const int nt = w + t3 * 8;
        #pragma unroll
        for (int kf = 0; kf < 4; ++kf) {
            Wa[t3][kf] = wf[OFF_DWHH0 + (nt * 4 + kf) * 64 + L];
            Wb[t3][kf] = wf[OFF_DWIH1 + (nt * 4 + kf) * 64 + L];
            Wc[t3][kf] = wf[OFF_DWHH1 + (nt * 4 + kf) * 64 + L];
        }
    }
    for (int i = t; i < 1024; i += NT) fw1l[i] = ((const uint4*)wf)[OFF_FW1 + i];

    const float d0_rz = SC_RZ * (dbih0[col] + dbhh0[col]);
    const float d0_zz = SC_RZ * (dbih0[HD + col] + dbhh0[HD + col]);
    const float d0_in = SC_N * dbih0[2 * HD + col];
    const float d0_hn = SC_N * dbhh0[2 * HD + col];
    const float d1_rz = SC_RZ * (dbih1[col] + dbhh1[col]);
    const float d1_zz = SC_RZ * (dbih1[HD + col] + dbhh1[HD + col]);
    const float d1_in = SC_N * dbih1[2 * HD + col];
    const float d1_hn = SC_N * dbhh1[2 * HD + col];
    const float w0r = SC_RZ * dWih0[col];
    const float w0z = SC_RZ * dWih0[HD + col];
    const float w0n = SC_N * dWih0[2 * HD + col];
    float f1bv[4], w2v[4];
    #pragma unroll
    for (int nt = 0; nt < 4; ++nt) {
        f1bv[nt] = fb1[nt * 16 + col16];
        w2v[nt]  = fW2[nt * 16 + col16];
    }
    const float fb2v = fb2[0];
    float ivr[2] = {0.f, 0.f};

    // prologue: ghA from h0_enc, then combine h0(0) (inp(-1)=0) -> h0f[0]
    {
        short8 Ah[4];
        #pragma unroll
        for (int kf = 0; kf < 4; ++kf)
            Ah[kf] = *(const short8*)&h0f[0][kf][L * 8];
        f32x4 g0 = MF(Ah[0], Wa[0][0], zf);
        f32x4 g1 = MF(Ah[0], Wa[1][0], zf);
        f32x4 g2 = MF(Ah[0], Wa[2][0], zf);
        #pragma unroll
        for (int kf = 1; kf < 4; ++kf) {
            g0 = MF(Ah[kf], Wa[0][kf], g0);
            g1 = MF(Ah[kf], Wa[1][kf], g1);
            g2 = MF(Ah[kf], Wa[2][kf], g2);
        }
        float g0e[2], g1e[2], g2e[2];
        spread2(g0, g0e[0], g0e[1]);
        spread2(g1, g1e[0], g1e[1]);
        spread2(g2, g2e[0], g2e[1]);
        barrier_lds();   // everyone done reading h0f[0] before overwrite
        ushort_t* wbp = &(&h0f[0][0][0])[0 + hwoE];
        #pragma unroll
        for (int e = 0; e < 2; ++e) {
            const float rg = sig2(g0e[e] + d0_rz);
            const float zg = sig2(g1e[e] + d0_zz);
            const float ng = fmaf(2.f, sig2(d0_in + rg * (g2e[e] + d0_hn)), -1.f);
            const float hn = fmaf(zg, h0r[e] - ng, ng);
            h0r[e] = hn;
            wbp[e * 8] = f2bf_h(hn);
        }
    }
    barrier_lds();

    // ---------------- decoder: 2 balanced phases/step, unrolled x2 ---------
    // h0(s) in h0f[s&1]; h1(s) in h1f[s&1] (h1(-1) in h1f[1]).
    for (int s = 0; s < TOUT; s += 2) {
        DEC_BODY(s, 0, 1);
        DEC_BODY(s + 1, 1, 0);
    }
}

extern "C" void kernel_launch(void* const* d_in, const int* in_sizes, int n_in,
                              void* d_out, int out_size, void* d_ws, size_t ws_size,
                              hipStream_t stream) {
    const float* x     = (const float*)d_in[0];
    const float* eWih0 = (const float*)d_in[1];
    const float* eWhh0 = (const float*)d_in[2];
    const float* ebih0 = (const float*)d_in[3];
    const float* ebhh0 = (const float*)d_in[4];
    const float* eWih1 = (const float*)d_in[5];
    const float* eWhh1 = (const float*)d_in[6];
    const float* ebih1 = (const float*)d_in[7];
    const float* ebhh1 = (const float*)d_in[8];
    const float* dWih0 = (const float*)d_in[9];
    const float* dWhh0 = (const float*)d_in[10];
    const float* dbih0 = (const float*)d_in[11];
    const float* dbhh0 = (const float*)d_in[12];
    const float* dWih1 = (const float*)d_in[13];
    const float* dWhh1 = (const float*)d_in[14];
    const float* dbih1 = (const float*)d_in[15];
    const float* dbhh1 = (const float*)d_in[16];
    const float* fW1   = (const float*)d_in[17];
    const float* fb1   = (const float*)d_in[18];
    const float* fW2   = (const float*)d_in[19];
    const float* fb2   = (const float*)d_in[20];
    float* out = (float*)d_out;

    hipLaunchKernelGGL(prep_kernel, dim3(616), dim3(64), 0, stream,
                       eWhh0, eWih1, eWhh1, dWhh0, dWih1, dWhh1, eWih0, fW1,
                       (uint4*)d_ws);
    hipLaunchKernelGGL(gru_seq2seq_kernel, dim3(NB), dim3(NT), 0, stream,
                       x, ebih0, ebhh0, ebih1, ebhh1,
                       dWih0, dbih0, dbhh0, dbih1, dbhh1,
                       fb1, fW2, fb2,
                       (const short8*)d_ws, out);
}